// Round 3
// baseline (11888.581 us; speedup 1.0000x reference)
//
#include <hip/hip_runtime.h>
#include <stdint.h>
#include <string.h>
#include <stdlib.h>

#define JAX_PARTITIONABLE 1

namespace {

constexpr int kW = 45, kH = 30, kD = 13;
constexpr int NVID = kW * kH * kD;          // 17550
constexpr int TEXT = 226;
constexpr int LSEQ = TEXT + NVID;           // 17776
constexpr int BLKSZ = 128;
constexpr int NBLK = 139;
constexpr int LPAD = NBLK * BLKSZ;          // 17792
constexpr int NKEEP = 32;
constexpr int NS = NBLK * NKEEP;            // 4448
constexpr int NH = 8;
constexpr int DD = 64;
constexpr int VLAST = LSEQ - (NBLK - 1) * BLKSZ;  // 112
constexpr float SCALE = 0.125f;
constexpr float LN2F = 0.69314718055994530942f;

// ---------------- workspace layout (float units) ----------------
constexpr long SZ_R  = (long)NH * LPAD * DD;        // 9109504
constexpr long SZ_S  = (long)NH * NS * DD;          // 2277376
constexpr long SZ_PL = (long)NH * NBLK * NBLK;      // 154568
constexpr long SZ_KP = (long)NH * NBLK * 112 * DD;  // 7970816
constexpr long SZ_O  = (long)NH * LSEQ * DD;        // 9101312
constexpr long F_QR = 0;
constexpr long F_KR = F_QR + SZ_R;
constexpr long F_VR = F_KR + SZ_R;
constexpr long F_SQ = F_VR + SZ_R;
constexpr long F_SK = F_SQ + SZ_S;
constexpr long F_PL = F_SK + SZ_S;
constexpr long F_KP = F_PL + SZ_PL;
constexpr long F_VP = F_KP + SZ_KP;
constexpr long F_MK = F_VP + SZ_KP;                 // int32: NH*NBLK*NBLK
constexpr long F_OR = F_MK + SZ_PL;                 // outr (rearranged-order output)
constexpr long F_TB = F_OR + SZ_O;                  // int32 tables
constexpr int TAB_INTS = 2 * LSEQ + 2 * NH * NKEEP; // inmap + outgather + qidx + kidx

// ============================ host: gilbert =============================
// NOTE: faithful port of the PROBLEM's _gen3d, including the volume-deficient
// regular-else branch (first call uses a2, not a). The curve yields n <= NVID
// cells; o2g keeps trailing zeros and g2o keeps zeros for missed cells,
// exactly like the reference's numpy zeros-arrays.
struct Gil { int* out; int n; };
static inline int sgn_i(int v) { return (v > 0) - (v < 0); }
static inline int fd2(int a) { return a >= 0 ? a / 2 : -((-a + 1) / 2); }  // floor div 2

static void gen3d(Gil& G, int x, int y, int z,
                  int ax, int ay, int az,
                  int bx, int by, int bz,
                  int cx, int cy, int cz) {
  int w = abs(ax + ay + az), h = abs(bx + by + bz), d = abs(cx + cy + cz);
  int dax = sgn_i(ax), day = sgn_i(ay), daz = sgn_i(az);
  int dbx = sgn_i(bx), dby = sgn_i(by), dbz = sgn_i(bz);
  int dcx = sgn_i(cx), dcy = sgn_i(cy), dcz = sgn_i(cz);
  if (h == 1 && d == 1) { for (int i = 0; i < w; i++) { G.out[G.n++] = x + kW * (y + kH * z); x += dax; y += day; z += daz; } return; }
  if (w == 1 && d == 1) { for (int i = 0; i < h; i++) { G.out[G.n++] = x + kW * (y + kH * z); x += dbx; y += dby; z += dbz; } return; }
  if (w == 1 && h == 1) { for (int i = 0; i < d; i++) { G.out[G.n++] = x + kW * (y + kH * z); x += dcx; y += dcy; z += dcz; } return; }
  int ax2 = fd2(ax), ay2 = fd2(ay), az2 = fd2(az);
  int bx2 = fd2(bx), by2 = fd2(by), bz2 = fd2(bz);
  int cx2 = fd2(cx), cy2 = fd2(cy), cz2 = fd2(cz);
  int w2 = abs(ax2 + ay2 + az2), h2 = abs(bx2 + by2 + bz2), d2 = abs(cx2 + cy2 + cz2);
  if ((w2 & 1) && w > 2) { ax2 += dax; ay2 += day; az2 += daz; }
  if ((h2 & 1) && h > 2) { bx2 += dbx; by2 += dby; bz2 += dbz; }
  if ((d2 & 1) && d > 2) { cx2 += dcx; cy2 += dcy; cz2 += dcz; }
  if (2 * w > 3 * h && 2 * w > 3 * d) {
    gen3d(G, x, y, z, ax2, ay2, az2, bx, by, bz, cx, cy, cz);
    gen3d(G, x + ax2, y + ay2, z + az2, ax - ax2, ay - ay2, az - az2, bx, by, bz, cx, cy, cz);
  } else if (3 * h > 4 * d) {
    gen3d(G, x, y, z, bx2, by2, bz2, cx, cy, cz, ax2, ay2, az2);
    gen3d(G, x + bx2, y + by2, z + bz2, ax, ay, az, bx - bx2, by - by2, bz - bz2, cx, cy, cz);
    gen3d(G, x + (ax - dax) + (bx2 - dbx), y + (ay - day) + (by2 - dby), z + (az - daz) + (bz2 - dbz),
          -bx2, -by2, -bz2, cx, cy, cz, -(ax - ax2), -(ay - ay2), -(az - az2));
  } else if (3 * d > 4 * h) {
    gen3d(G, x, y, z, cx2, cy2, cz2, ax2, ay2, az2, bx, by, bz);
    gen3d(G, x + cx2, y + cy2, z + cz2, ax, ay, az, bx, by, bz, cx - cx2, cy - cy2, cz - cz2);
    gen3d(G, x + (ax - dax) + (cx2 - dcx), y + (ay - day) + (cy2 - dcy), z + (az - daz) + (cz2 - dcz),
          -cx2, -cy2, -cz2, -(ax - ax2), -(ay - ay2), -(az - az2), bx, by, bz);
  } else {
    gen3d(G, x, y, z, bx2, by2, bz2, cx2, cy2, cz2, ax2, ay2, az2);
    gen3d(G, x + bx2, y + by2, z + bz2, cx, cy, cz, ax2, ay2, az2, bx - bx2, by - by2, bz - bz2);
    gen3d(G, x + (bx2 - dbx) + (cx - dcx), y + (by2 - dby) + (cy - dcy), z + (bz2 - dbz) + (cz - dcz),
          ax, ay, az, -bx2, -by2, -bz2, -(cx - cx2), -(cy - cy2), -(cz - cz2));
    gen3d(G, x + (ax - dax) + bx2 + (cx - dcx), y + (ay - day) + by2 + (cy - dcy), z + (az - daz) + bz2 + (cz - dcz),
          -cx, -cy, -cz, -(ax - ax2), -(ay - ay2), -(az - az2), bx - bx2, by - by2, bz - bz2);
  }
}

// ============================ host: threefry ============================
static void tf2x32(uint32_t k0, uint32_t k1, uint32_t x0, uint32_t x1,
                   uint32_t& o0, uint32_t& o1) {
  uint32_t ks0 = k0, ks1 = k1, ks2 = k0 ^ k1 ^ 0x1BD11BDAu;
  const uint32_t ks[3] = {ks0, ks1, ks2};
  const int rot[2][4] = {{13, 15, 26, 6}, {17, 29, 16, 24}};
  x0 += ks[0]; x1 += ks[1];
  for (int i = 0; i < 5; i++) {
    for (int j = 0; j < 4; j++) {
      int rr = rot[i & 1][j];
      x0 += x1;
      x1 = (x1 << rr) | (x1 >> (32 - rr));
      x1 ^= x0;
    }
    x0 += ks[(i + 1) % 3];
    x1 += ks[(i + 2) % 3] + (uint32_t)(i + 1);
  }
  o0 = x0; o1 = x1;
}

static inline float bits_to_unit(uint32_t bits) {
  uint32_t fb = (bits >> 9) | 0x3f800000u;
  float f; memcpy(&f, &fb, 4);
  return f - 1.0f;
}

static void fill_idx(uint32_t K0, uint32_t K1, int* dst) {
  float u[NH * BLKSZ];
#if JAX_PARTITIONABLE
  for (int i = 0; i < NH * BLKSZ; i++) {
    uint32_t a, b; tf2x32(K0, K1, 0u, (uint32_t)i, a, b);
    u[i] = bits_to_unit(a ^ b);
  }
#else
  {
    const int n = NH * BLKSZ, hn = n / 2;
    for (int i = 0; i < hn; i++) {
      uint32_t a, b; tf2x32(K0, K1, (uint32_t)i, (uint32_t)(hn + i), a, b);
      u[i] = bits_to_unit(a);
      u[hn + i] = bits_to_unit(b);
    }
  }
#endif
  for (int h = 0; h < NH; h++) {
    const float* row = u + h * BLKSZ;
    bool used[BLKSZ] = {false};
    for (int r = 0; r < NKEEP; r++) {
      int best = -1; float bv = -2.0f;
      for (int g = 0; g < BLKSZ; g++)
        if (!used[g] && row[g] > bv) { bv = row[g]; best = g; }
      used[best] = true;
      dst[h * NKEEP + r] = best;
    }
  }
}

static void build_tables(int* tab) {
  static int yields[NVID];
  static int o2g_buf[NVID];
  static int g2o_buf[NVID];
  memset(o2g_buf, 0, sizeof(o2g_buf));
  memset(g2o_buf, 0, sizeof(g2o_buf));
  Gil G{yields, 0};
  // top-level dispatch: w=45 >= h=30 >= d=13
  gen3d(G, 0, 0, 0, kW, 0, 0, 0, kD == 0 ? 0 : 0 + 0 + 0 + 0 + kH, 0, 0, 0, kD);
  // (the line above is just gen3d(G,0,0,0, 45,0,0, 0,30,0, 0,0,13) -- written
  //  plainly below to avoid any confusion; reset and redo)
  G.n = 0;
  gen3d(G, 0, 0, 0, kW, 0, 0, 0, kH, 0, 0, 0, kD);
  int n = G.n;                      // may be < NVID (deficient recursion)
  if (n > NVID) n = NVID;
  for (int g = 0; g < n; g++) o2g_buf[g] = yields[g];
  for (int g = 0; g < n; g++) g2o_buf[yields[g]] = g;

  int* inmap = tab;                 // [LSEQ] rearranged row -> original row
  int* outg  = tab + LSEQ;          // [LSEQ] final row -> rearranged row
  for (int g = 0; g < NVID; g++) inmap[g] = TEXT + o2g_buf[g];
  for (int t = 0; t < TEXT; t++) inmap[NVID + t] = t;
  for (int r = 0; r < TEXT; r++) outg[r] = NVID + r;
  for (int c = 0; c < NVID; c++) outg[TEXT + c] = g2o_buf[c];

  uint32_t kq0, kq1, kk0, kk1;
#if JAX_PARTITIONABLE
  tf2x32(0, 0, 0, 0, kq0, kq1);
  tf2x32(0, 0, 0, 1, kk0, kk1);
#else
  {
    uint32_t y00, y10, y01, y11;
    tf2x32(0, 0, 0, 2, y00, y10);
    tf2x32(0, 0, 1, 3, y01, y11);
    kq0 = y00; kq1 = y01; kk0 = y10; kk1 = y11;
  }
#endif
  fill_idx(kq0, kq1, tab + 2 * LSEQ);
  fill_idx(kk0, kk1, tab + 2 * LSEQ + NH * NKEEP);
}

}  // namespace

// ============================ device kernels ============================

__global__ __launch_bounds__(256) void k_rearr(
    const float* __restrict__ q, const float* __restrict__ k, const float* __restrict__ v,
    float* __restrict__ qr, float* __restrict__ kr, float* __restrict__ vr,
    const int* __restrict__ inmap) {
  long rid = (long)blockIdx.x * 4 + (threadIdx.x >> 6);
  int d = threadIdx.x & 63;
  const long total = 3L * NH * LPAD;
  if (rid >= total) return;
  int tsel = (int)(rid / ((long)NH * LPAD));
  long rem = rid - (long)tsel * NH * LPAD;
  int h = (int)(rem / LPAD);
  int i = (int)(rem % LPAD);
  const float* src = tsel == 0 ? q : (tsel == 1 ? k : v);
  float* dst = tsel == 0 ? qr : (tsel == 1 ? kr : vr);
  float val = 0.f;
  if (i < LSEQ) val = src[((long)h * LSEQ + inmap[i]) * DD + d];
  dst[((long)h * LPAD + i) * DD + d] = val;
}

__global__ __launch_bounds__(256) void k_sample(
    const float* __restrict__ qr, const float* __restrict__ kr,
    float* __restrict__ sq, float* __restrict__ sk,
    const int* __restrict__ qidx, const int* __restrict__ kidx) {
  long rid = (long)blockIdx.x * 4 + (threadIdx.x >> 6);
  int d = threadIdx.x & 63;
  const long total = 2L * NH * NS;
  if (rid >= total) return;
  int tsel = (int)(rid / ((long)NH * NS));
  long rem = rid - (long)tsel * NH * NS;
  int h = (int)(rem / NS);
  int s = (int)(rem % NS);
  int b = s / NKEEP, t = s % NKEEP;
  const int* idx = tsel ? kidx : qidx;
  int p = b * BLKSZ + idx[h * NKEEP + t];
  if (p >= LSEQ) p = LSEQ - 1;  // edge padding
  const float* src = tsel ? kr : qr;
  float* dst = tsel ? sk : sq;
  dst[((long)h * NS + s) * DD + d] = src[((long)h * LPAD + p) * DD + d];
}

// pool[h][qb][kb] = sum over 32 sampled q-rows of softmax-mass falling in k-block kb
__global__ __launch_bounds__(256) void k_scores_pool(
    const float* __restrict__ sq, const float* __restrict__ sk, float* __restrict__ pool) {
  __shared__ float kt[NKEEP * DD];          // 32x64 staged k tile
  __shared__ float bins[NKEEP * NBLK];      // [q-row][k-block] exp sums
  __shared__ float bpart[4][NKEEP];
  __shared__ float invden[NKEEP];
  int h = blockIdx.x / NBLK, qb = blockIdx.x % NBLK;
  int t = threadIdx.x;
  int r = t & 31;
  int c = t >> 5;  // 0..7
  float4 qv[16];
  {
    const float4* q4 = (const float4*)(sq + ((long)h * NS + qb * NKEEP + r) * DD);
#pragma unroll
    for (int i = 0; i < 16; i++) qv[i] = q4[i];
  }
  for (int i = t; i < NKEEP * NBLK; i += 256) bins[i] = 0.f;
  const float* skh = sk + (long)h * NS * DD;
  for (int kb = 0; kb < NBLK; kb++) {
    __syncthreads();
    const float4* src4 = (const float4*)(skh + (long)kb * NKEEP * DD);
    for (int i = t; i < NKEEP * DD / 4; i += 256) ((float4*)kt)[i] = src4[i];
    __syncthreads();
    float acc = 0.f;
#pragma unroll
    for (int i = 0; i < 4; i++) {
      int krow = c * 4 + i;
      const float4* k4 = (const float4*)(kt + krow * DD);
      float s = 0.f;
#pragma unroll
      for (int d4 = 0; d4 < 16; d4++) {
        float4 a = qv[d4], b = k4[d4];
        s += a.x * b.x + a.y * b.y + a.z * b.z + a.w * b.w;
      }
      acc += __expf(s * SCALE);  // no max-sub needed: |s*SCALE| <~ 6 in fp32
    }
    acc += __shfl_xor(acc, 32);
    if ((t & 32) == 0) bpart[t >> 6][r] = acc;
    __syncthreads();
    if (t < NKEEP) bins[t * NBLK + kb] = bpart[0][t] + bpart[1][t] + bpart[2][t] + bpart[3][t];
  }
  __syncthreads();
  if (t < NKEEP) {
    float s = 0.f;
    for (int kb = 0; kb < NBLK; kb++) s += bins[t * NBLK + kb];
    invden[t] = 1.0f / s;
  }
  __syncthreads();
  if (t < NBLK) {
    float s = 0.f;
    for (int r2 = 0; r2 < NKEEP; r2++) s += bins[r2 * NBLK + t] * invden[r2];
    pool[((long)h * NBLK + qb) * NBLK + t] = s;
  }
}

__global__ __launch_bounds__(192) void k_mask(
    const float* __restrict__ pool, int* __restrict__ mask) {
  __shared__ float row[NBLK];
  int h = blockIdx.x / NBLK, i = blockIdx.x % NBLK;
  int t = threadIdx.x;
  const float* pr = pool + ((long)h * NBLK + i) * NBLK;
  if (t < NBLK) row[t] = pr[t];
  __syncthreads();
  if (t < NBLK) {
    float pv = row[t];
    int rank = 0;
    for (int j = 0; j < NBLK; j++) {
      float o = row[j];
      rank += (o > pv) || (o == pv && j < t);
    }
    int val = 0;
    if (rank < 6) val = 1;
    else if (rank < 20) val = 2;
    else if (rank < 34) val = 4;
    else if (rank < 69) val = 8;
    if (t >= NBLK - 2) val = 1;
    if (i >= NBLK - 2) val = 1;
    mask[((long)h * NBLK + i) * NBLK + t] = val;
  }
}

// pooled K/V for levels m=2,4,8; compact 112 rows per (h, block):
//   [0..63]: m=2, [64..95]: m=4, [96..111]: m=8
__global__ __launch_bounds__(256) void k_poolkv(
    const float* __restrict__ kr, const float* __restrict__ vr,
    float* __restrict__ Kp, float* __restrict__ Vp) {
  long rid = (long)blockIdx.x * 4 + (threadIdx.x >> 6);
  int d = threadIdx.x & 63;
  const long total = 2L * NH * NBLK * 112;
  if (rid >= total) return;
  int tsel = (int)(rid / ((long)NH * NBLK * 112));
  long rem = rid - (long)tsel * NH * NBLK * 112;
  int h = (int)(rem / (NBLK * 112));
  int rem2 = (int)(rem % (NBLK * 112));
  int j = rem2 / 112, p = rem2 % 112;
  int m, g;
  if (p < 64) { m = 2; g = p; }
  else if (p < 96) { m = 4; g = p - 64; }
  else { m = 8; g = p - 96; }
  const float* src = tsel ? vr : kr;
  const float* base = src + ((long)h * LPAD + j * BLKSZ + g * m) * DD + d;
  float sum = 0.f;
  for (int r2 = 0; r2 < m; r2++) sum += base[(long)r2 * DD];
  float* dst = tsel ? Vp : Kp;
  dst[(((long)h * NBLK + j) * 112 + p) * DD + d] = sum / (float)m;
}

__global__ __launch_bounds__(256) void k_attn(
    const float* __restrict__ qr,
    const float* __restrict__ kr, const float* __restrict__ vr,
    const float* __restrict__ Kp, const float* __restrict__ Vp,
    const int* __restrict__ mask,
    float* __restrict__ outr) {
  __shared__ float Kt[64 * DD];   // 16 KB chunk
  __shared__ float Vt[64 * DD];   // 16 KB chunk
  __shared__ int mrow[NBLK];
  int h = blockIdx.x / NBLK, qi = blockIdx.x % NBLK;
  int t = threadIdx.x;
  int r = t >> 1, half = t & 1;
  if (t < NBLK) mrow[t] = mask[((long)h * NBLK + qi) * NBLK + t];
  float4 qv[8];
  {
    const float4* q4 = (const float4*)(qr + ((long)h * LPAD + qi * BLKSZ + r) * DD + half * 32);
#pragma unroll
    for (int i = 0; i < 8; i++) qv[i] = q4[i];
  }
  float4 av[8];
#pragma unroll
  for (int i = 0; i < 8; i++) av[i] = make_float4(0.f, 0.f, 0.f, 0.f);
  float lrun = 0.f;
  __syncthreads();
  for (int j = 0; j < NBLK; j++) {
    int mv = mrow[j];
    if (mv == 0) continue;
    int lvl = (mv == 1) ? 0 : (mv == 2) ? 1 : (mv == 4) ? 2 : 3;
    int Gv = ((j == NBLK - 1) ? VLAST : BLKSZ) >> lvl;
    float bias = lvl * LN2F;
    const float* Ksrc; const float* Vsrc;
    if (lvl == 0) {
      Ksrc = kr + ((long)h * LPAD + (long)j * BLKSZ) * DD;
      Vsrc = vr + ((long)h * LPAD + (long)j * BLKSZ) * DD;
    } else {
      int loff = (lvl == 1) ? 0 : (lvl == 2) ? 64 : 96;
      Ksrc = Kp + (((long)h * NBLK + j) * 112 + loff) * DD;
      Vsrc = Vp + (((long)h * NBLK + j) * 112 + loff) * DD;
    }
    for (int base = 0; base < Gv; base += 64) {
      int cnt = Gv - base; if (cnt > 64) cnt = 64;
      int n4 = cnt * (DD / 4);
      const float4* Ks4 = (const float4*)(Ksrc + (long)base * DD);
      const float4* Vs4 = (const float4*)(Vsrc + (long)base * DD);
      __syncthreads();
      for (int i4 = t; i4 < n4; i4 += 256) {
        ((float4*)Kt)[i4] = Ks4[i4];
        ((float4*)Vt)[i4] = Vs4[i4];
      }
      __syncthreads();
      for (int g = 0; g < cnt; g++) {
        const float4* kt4 = (const float4*)(Kt + g * DD + half * 32);
        float part = 0.f;
#pragma unroll
        for (int i = 0; i < 8; i++) {
          float4 b = kt4[i];
          part += qv[i].x * b.x + qv[i].y * b.y + qv[i].z * b.z + qv[i].w * b.w;
        }
        float s = part + __shfl_xor(part, 1);
        s = s * SCALE + bias;
        float p = __expf(s);   // |s| small enough: no running max needed in fp32
        lrun += p;
        const float4* vt4 = (const float4*)(Vt + g * DD + half * 32);
#pragma unroll
        for (int i = 0; i < 8; i++) {
          float4 vv = vt4[i];
          av[i].x += p * vv.x; av[i].y += p * vv.y;
          av[i].z += p * vv.z; av[i].w += p * vv.w;
        }
      }
    }
  }
  int grow = qi * BLKSZ + r;
  if (grow < LSEQ) {
    float inv = 1.0f / lrun;
    float4* o4 = (float4*)(outr + ((long)h * LSEQ + grow) * DD + half * 32);
#pragma unroll
    for (int i = 0; i < 8; i++) {
      float4 w = av[i];
      w.x *= inv; w.y *= inv; w.z *= inv; w.w *= inv;
      o4[i] = w;
    }
  }
}

// final gather: out[h][r] = outr[h][outg[r]]  (writes EVERY output element)
__global__ __launch_bounds__(256) void k_out(
    const float* __restrict__ outr, const int* __restrict__ outg,
    float* __restrict__ out) {
  long rid = (long)blockIdx.x * 4 + (threadIdx.x >> 6);
  int d = threadIdx.x & 63;
  const long total = (long)NH * LSEQ;
  if (rid >= total) return;
  int h = (int)(rid / LSEQ);
  int r = (int)(rid % LSEQ);
  int src = outg[r];
  out[((long)h * LSEQ + r) * DD + d] = outr[((long)h * LSEQ + src) * DD + d];
}

// ============================ launch ============================

extern "C" void kernel_launch(void* const* d_in, const int* in_sizes, int n_in,
                              void* d_out, int out_size, void* d_ws, size_t ws_size,
                              hipStream_t stream) {
  (void)in_sizes; (void)n_in; (void)out_size; (void)ws_size;
  const float* q = (const float*)d_in[0];
  const float* k = (const float*)d_in[1];
  const float* v = (const float*)d_in[2];
  float* ws = (float*)d_ws;
  float* out = (float*)d_out;

  static int* htab = nullptr;
  if (!htab) { (void)hipHostMalloc((void**)&htab, TAB_INTS * sizeof(int)); }
  build_tables(htab);

  int* dtab = (int*)(ws + F_TB);
  int* inmap = dtab;
  int* outg = dtab + LSEQ;
  int* qidx = dtab + 2 * LSEQ;
  int* kidx = qidx + NH * NKEEP;
  int* dmask = (int*)(ws + F_MK);
  float* qr = ws + F_QR; float* kr = ws + F_KR; float* vr = ws + F_VR;
  float* sq = ws + F_SQ; float* sk = ws + F_SK; float* pool = ws + F_PL;
  float* Kp = ws + F_KP; float* Vp = ws + F_VP;
  float* outr = ws + F_OR;

  hipMemcpyAsync(dtab, htab, TAB_INTS * sizeof(int), hipMemcpyHostToDevice, stream);

  {
    long rows = 3L * NH * LPAD;
    k_rearr<<<dim3((unsigned)((rows + 3) / 4)), 256, 0, stream>>>(q, k, v, qr, kr, vr, inmap);
  }
  {
    long rows = 2L * NH * NS;
    k_sample<<<dim3((unsigned)((rows + 3) / 4)), 256, 0, stream>>>(qr, kr, sq, sk, qidx, kidx);
  }
  k_scores_pool<<<dim3(NH * NBLK), 256, 0, stream>>>(sq, sk, pool);
  k_mask<<<dim3(NH * NBLK), 192, 0, stream>>>(pool, dmask);
  {
    long rows = 2L * NH * NBLK * 112;
    k_poolkv<<<dim3((unsigned)((rows + 3) / 4)), 256, 0, stream>>>(kr, vr, Kp, Vp);
  }
  k_attn<<<dim3(NH * NBLK), 256, 0, stream>>>(qr, kr, vr, Kp, Vp, dmask, outr);
  {
    long rows = (long)NH * LSEQ;
    k_out<<<dim3((unsigned)((rows + 3) / 4)), 256, 0, stream>>>(outr, outg, out);
  }
}

// Round 4
// 1431.116 us; speedup vs baseline: 8.3072x; 8.3072x over previous
//
#include <hip/hip_runtime.h>
#include <stdint.h>
#include <string.h>
#include <stdlib.h>

#define JAX_PARTITIONABLE 1

namespace {

constexpr int kW = 45, kH = 30, kD = 13;
constexpr int NVID = kW * kH * kD;          // 17550
constexpr int TEXT = 226;
constexpr int LSEQ = TEXT + NVID;           // 17776
constexpr int BLKSZ = 128;
constexpr int NBLK = 139;
constexpr int LPAD = NBLK * BLKSZ;          // 17792
constexpr int NKEEP = 32;
constexpr int NS = NBLK * NKEEP;            // 4448
constexpr int NH = 8;
constexpr int DD = 64;
constexpr int VLAST = LSEQ - (NBLK - 1) * BLKSZ;  // 112
constexpr float SCALE = 0.125f;
constexpr float LN2F = 0.69314718055994530942f;
constexpr int MAXG = 1116;                  // max 16-row groups per (h,qb): 138*8+7 (+dummy)

// ---------------- workspace layout (float units) ----------------
constexpr long SZ_R  = (long)NH * LPAD * DD;        // 9109504
constexpr long SZ_S  = (long)NH * NS * DD;          // 2277376
constexpr long SZ_PL = (long)NH * NBLK * NBLK;      // 154568
constexpr long SZ_KP = (long)NH * NBLK * 112 * DD;  // 7970816
constexpr long SZ_O  = (long)NH * LSEQ * DD;        // 9101312
constexpr long F_QR = 0;
constexpr long F_KR = F_QR + SZ_R;
constexpr long F_VR = F_KR + SZ_R;
constexpr long F_SQ = F_VR + SZ_R;
constexpr long F_SK = F_SQ + SZ_S;
constexpr long F_PL = F_SK + SZ_S;
constexpr long F_KP = F_PL + SZ_PL;
constexpr long F_VP = F_KP + SZ_KP;
constexpr long F_MK = F_VP + SZ_KP;                 // int32: NH*NBLK*NBLK
constexpr long F_OR = F_MK + SZ_PL;                 // outr (rearranged-order output)
constexpr long F_TB = F_OR + SZ_O;                  // int32 tables
constexpr int TAB_INTS = 2 * LSEQ + 2 * NH * NKEEP; // inmap + outgather + qidx + kidx

// ============================ host: gilbert =============================
// Faithful port of the PROBLEM's _gen3d (volume-deficient regular-else branch
// included). o2g keeps trailing zeros; g2o keeps zeros for missed cells.
struct Gil { int* out; int n; };
static inline int sgn_i(int v) { return (v > 0) - (v < 0); }
static inline int fd2(int a) { return a >= 0 ? a / 2 : -((-a + 1) / 2); }  // floor div 2

static void gen3d(Gil& G, int x, int y, int z,
                  int ax, int ay, int az,
                  int bx, int by, int bz,
                  int cx, int cy, int cz) {
  int w = abs(ax + ay + az), h = abs(bx + by + bz), d = abs(cx + cy + cz);
  int dax = sgn_i(ax), day = sgn_i(ay), daz = sgn_i(az);
  int dbx = sgn_i(bx), dby = sgn_i(by), dbz = sgn_i(bz);
  int dcx = sgn_i(cx), dcy = sgn_i(cy), dcz = sgn_i(cz);
  if (h == 1 && d == 1) { for (int i = 0; i < w; i++) { G.out[G.n++] = x + kW * (y + kH * z); x += dax; y += day; z += daz; } return; }
  if (w == 1 && d == 1) { for (int i = 0; i < h; i++) { G.out[G.n++] = x + kW * (y + kH * z); x += dbx; y += dby; z += dbz; } return; }
  if (w == 1 && h == 1) { for (int i = 0; i < d; i++) { G.out[G.n++] = x + kW * (y + kH * z); x += dcx; y += dcy; z += dcz; } return; }
  int ax2 = fd2(ax), ay2 = fd2(ay), az2 = fd2(az);
  int bx2 = fd2(bx), by2 = fd2(by), bz2 = fd2(bz);
  int cx2 = fd2(cx), cy2 = fd2(cy), cz2 = fd2(cz);
  int w2 = abs(ax2 + ay2 + az2), h2 = abs(bx2 + by2 + bz2), d2 = abs(cx2 + cy2 + cz2);
  if ((w2 & 1) && w > 2) { ax2 += dax; ay2 += day; az2 += daz; }
  if ((h2 & 1) && h > 2) { bx2 += dbx; by2 += dby; bz2 += dbz; }
  if ((d2 & 1) && d > 2) { cx2 += dcx; cy2 += dcy; cz2 += dcz; }
  if (2 * w > 3 * h && 2 * w > 3 * d) {
    gen3d(G, x, y, z, ax2, ay2, az2, bx, by, bz, cx, cy, cz);
    gen3d(G, x + ax2, y + ay2, z + az2, ax - ax2, ay - ay2, az - az2, bx, by, bz, cx, cy, cz);
  } else if (3 * h > 4 * d) {
    gen3d(G, x, y, z, bx2, by2, bz2, cx, cy, cz, ax2, ay2, az2);
    gen3d(G, x + bx2, y + by2, z + bz2, ax, ay, az, bx - bx2, by - by2, bz - bz2, cx, cy, cz);
    gen3d(G, x + (ax - dax) + (bx2 - dbx), y + (ay - day) + (by2 - dby), z + (az - daz) + (bz2 - dbz),
          -bx2, -by2, -bz2, cx, cy, cz, -(ax - ax2), -(ay - ay2), -(az - az2));
  } else if (3 * d > 4 * h) {
    gen3d(G, x, y, z, cx2, cy2, cz2, ax2, ay2, az2, bx, by, bz);
    gen3d(G, x + cx2, y + cy2, z + cz2, ax, ay, az, bx, by, bz, cx - cx2, cy - cy2, cz - cz2);
    gen3d(G, x + (ax - dax) + (cx2 - dcx), y + (ay - day) + (cy2 - dcy), z + (az - daz) + (cz2 - dcz),
          -cx2, -cy2, -cz2, -(ax - ax2), -(ay - ay2), -(az - az2), bx, by, bz);
  } else {
    gen3d(G, x, y, z, bx2, by2, bz2, cx2, cy2, cz2, ax2, ay2, az2);
    gen3d(G, x + bx2, y + by2, z + bz2, cx, cy, cz, ax2, ay2, az2, bx - bx2, by - by2, bz - bz2);
    gen3d(G, x + (bx2 - dbx) + (cx - dcx), y + (by2 - dby) + (cy - dcy), z + (bz2 - dbz) + (cz - dcz),
          ax, ay, az, -bx2, -by2, -bz2, -(cx - cx2), -(cy - cy2), -(cz - cz2));
    gen3d(G, x + (ax - dax) + bx2 + (cx - dcx), y + (ay - day) + by2 + (cy - dcy), z + (az - daz) + bz2 + (cz - dcz),
          -cx, -cy, -cz, -(ax - ax2), -(ay - ay2), -(az - az2), bx - bx2, by - by2, bz - bz2);
  }
}

// ============================ host: threefry ============================
static void tf2x32(uint32_t k0, uint32_t k1, uint32_t x0, uint32_t x1,
                   uint32_t& o0, uint32_t& o1) {
  uint32_t ks0 = k0, ks1 = k1, ks2 = k0 ^ k1 ^ 0x1BD11BDAu;
  const uint32_t ks[3] = {ks0, ks1, ks2};
  const int rot[2][4] = {{13, 15, 26, 6}, {17, 29, 16, 24}};
  x0 += ks[0]; x1 += ks[1];
  for (int i = 0; i < 5; i++) {
    for (int j = 0; j < 4; j++) {
      int rr = rot[i & 1][j];
      x0 += x1;
      x1 = (x1 << rr) | (x1 >> (32 - rr));
      x1 ^= x0;
    }
    x0 += ks[(i + 1) % 3];
    x1 += ks[(i + 2) % 3] + (uint32_t)(i + 1);
  }
  o0 = x0; o1 = x1;
}

static inline float bits_to_unit(uint32_t bits) {
  uint32_t fb = (bits >> 9) | 0x3f800000u;
  float f; memcpy(&f, &fb, 4);
  return f - 1.0f;
}

static void fill_idx(uint32_t K0, uint32_t K1, int* dst) {
  float u[NH * BLKSZ];
#if JAX_PARTITIONABLE
  for (int i = 0; i < NH * BLKSZ; i++) {
    uint32_t a, b; tf2x32(K0, K1, 0u, (uint32_t)i, a, b);
    u[i] = bits_to_unit(a ^ b);
  }
#else
  {
    const int n = NH * BLKSZ, hn = n / 2;
    for (int i = 0; i < hn; i++) {
      uint32_t a, b; tf2x32(K0, K1, (uint32_t)i, (uint32_t)(hn + i), a, b);
      u[i] = bits_to_unit(a);
      u[hn + i] = bits_to_unit(b);
    }
  }
#endif
  for (int h = 0; h < NH; h++) {
    const float* row = u + h * BLKSZ;
    bool used[BLKSZ] = {false};
    for (int r = 0; r < NKEEP; r++) {
      int best = -1; float bv = -2.0f;
      for (int g = 0; g < BLKSZ; g++)
        if (!used[g] && row[g] > bv) { bv = row[g]; best = g; }
      used[best] = true;
      dst[h * NKEEP + r] = best;
    }
  }
}

static void build_tables(int* tab) {
  static int yields[NVID];
  static int o2g_buf[NVID];
  static int g2o_buf[NVID];
  memset(o2g_buf, 0, sizeof(o2g_buf));
  memset(g2o_buf, 0, sizeof(g2o_buf));
  Gil G{yields, 0};
  gen3d(G, 0, 0, 0, kW, 0, 0, 0, kH, 0, 0, 0, kD);
  int n = G.n;                      // may be < NVID (deficient recursion)
  if (n > NVID) n = NVID;
  for (int g = 0; g < n; g++) o2g_buf[g] = yields[g];
  for (int g = 0; g < n; g++) g2o_buf[yields[g]] = g;

  int* inmap = tab;                 // [LSEQ] rearranged row -> original row
  int* outg  = tab + LSEQ;          // [LSEQ] final row -> rearranged row
  for (int g = 0; g < NVID; g++) inmap[g] = TEXT + o2g_buf[g];
  for (int t = 0; t < TEXT; t++) inmap[NVID + t] = t;
  for (int r = 0; r < TEXT; r++) outg[r] = NVID + r;
  for (int c = 0; c < NVID; c++) outg[TEXT + c] = g2o_buf[c];

  uint32_t kq0, kq1, kk0, kk1;
#if JAX_PARTITIONABLE
  tf2x32(0, 0, 0, 0, kq0, kq1);
  tf2x32(0, 0, 0, 1, kk0, kk1);
#else
  {
    uint32_t y00, y10, y01, y11;
    tf2x32(0, 0, 0, 2, y00, y10);
    tf2x32(0, 0, 1, 3, y01, y11);
    kq0 = y00; kq1 = y01; kk0 = y10; kk1 = y11;
  }
#endif
  fill_idx(kq0, kq1, tab + 2 * LSEQ);
  fill_idx(kk0, kk1, tab + 2 * LSEQ + NH * NKEEP);
}

}  // namespace

// ============================ device helpers ============================

typedef __attribute__((ext_vector_type(8))) short short8v;   // 8 bf16 (4 VGPRs)
typedef __attribute__((ext_vector_type(4))) float f32x4;     // MFMA C/D

static __device__ inline unsigned short f2bf(float f) {
  unsigned u = __float_as_uint(f);
  unsigned r = u + 0x7FFFu + ((u >> 16) & 1u);  // RNE
  return (unsigned short)(r >> 16);
}
static __device__ inline float bf2f(unsigned short s) {
  return __uint_as_float(((unsigned)s) << 16);
}

// ============================ device kernels ============================

__global__ __launch_bounds__(256) void k_rearr(
    const float* __restrict__ q, const float* __restrict__ k, const float* __restrict__ v,
    float* __restrict__ qr, float* __restrict__ kr, float* __restrict__ vr,
    const int* __restrict__ inmap) {
  long rid = (long)blockIdx.x * 4 + (threadIdx.x >> 6);
  int d = threadIdx.x & 63;
  const long total = 3L * NH * LPAD;
  if (rid >= total) return;
  int tsel = (int)(rid / ((long)NH * LPAD));
  long rem = rid - (long)tsel * NH * LPAD;
  int h = (int)(rem / LPAD);
  int i = (int)(rem % LPAD);
  const float* src = tsel == 0 ? q : (tsel == 1 ? k : v);
  float* dst = tsel == 0 ? qr : (tsel == 1 ? kr : vr);
  float val = 0.f;
  if (i < LSEQ) val = src[((long)h * LSEQ + inmap[i]) * DD + d];
  dst[((long)h * LPAD + i) * DD + d] = val;
}

__global__ __launch_bounds__(256) void k_sample(
    const float* __restrict__ qr, const float* __restrict__ kr,
    float* __restrict__ sq, float* __restrict__ sk,
    const int* __restrict__ qidx, const int* __restrict__ kidx) {
  long rid = (long)blockIdx.x * 4 + (threadIdx.x >> 6);
  int d = threadIdx.x & 63;
  const long total = 2L * NH * NS;
  if (rid >= total) return;
  int tsel = (int)(rid / ((long)NH * NS));
  long rem = rid - (long)tsel * NH * NS;
  int h = (int)(rem / NS);
  int s = (int)(rem % NS);
  int b = s / NKEEP, t = s % NKEEP;
  const int* idx = tsel ? kidx : qidx;
  int p = b * BLKSZ + idx[h * NKEEP + t];
  if (p >= LSEQ) p = LSEQ - 1;  // edge padding
  const float* src = tsel ? kr : qr;
  float* dst = tsel ? sk : sq;
  dst[((long)h * NS + s) * DD + d] = src[((long)h * LPAD + p) * DD + d];
}

// pool[h][qb][kb] = sum over 32 sampled q-rows of softmax-mass falling in k-block kb
__global__ __launch_bounds__(256) void k_scores_pool(
    const float* __restrict__ sq, const float* __restrict__ sk, float* __restrict__ pool) {
  __shared__ float kt[NKEEP * DD];
  __shared__ float bins[NKEEP * NBLK];
  __shared__ float bpart[4][NKEEP];
  __shared__ float invden[NKEEP];
  int h = blockIdx.x / NBLK, qb = blockIdx.x % NBLK;
  int t = threadIdx.x;
  int r = t & 31;
  int c = t >> 5;
  float4 qv[16];
  {
    const float4* q4 = (const float4*)(sq + ((long)h * NS + qb * NKEEP + r) * DD);
#pragma unroll
    for (int i = 0; i < 16; i++) qv[i] = q4[i];
  }
  for (int i = t; i < NKEEP * NBLK; i += 256) bins[i] = 0.f;
  const float* skh = sk + (long)h * NS * DD;
  for (int kb = 0; kb < NBLK; kb++) {
    __syncthreads();
    const float4* src4 = (const float4*)(skh + (long)kb * NKEEP * DD);
    for (int i = t; i < NKEEP * DD / 4; i += 256) ((float4*)kt)[i] = src4[i];
    __syncthreads();
    float acc = 0.f;
#pragma unroll
    for (int i = 0; i < 4; i++) {
      int krow = c * 4 + i;
      const float4* k4 = (const float4*)(kt + krow * DD);
      float s = 0.f;
#pragma unroll
      for (int d4 = 0; d4 < 16; d4++) {
        float4 a = qv[d4], b = k4[d4];
        s += a.x * b.x + a.y * b.y + a.z * b.z + a.w * b.w;
      }
      acc += __expf(s * SCALE);
    }
    acc += __shfl_xor(acc, 32);
    if ((t & 32) == 0) bpart[t >> 6][r] = acc;
    __syncthreads();
    if (t < NKEEP) bins[t * NBLK + kb] = bpart[0][t] + bpart[1][t] + bpart[2][t] + bpart[3][t];
  }
  __syncthreads();
  if (t < NKEEP) {
    float s = 0.f;
    for (int kb = 0; kb < NBLK; kb++) s += bins[t * NBLK + kb];
    invden[t] = 1.0f / s;
  }
  __syncthreads();
  if (t < NBLK) {
    float s = 0.f;
    for (int r2 = 0; r2 < NKEEP; r2++) s += bins[r2 * NBLK + t] * invden[r2];
    pool[((long)h * NBLK + qb) * NBLK + t] = s;
  }
}

__global__ __launch_bounds__(192) void k_mask(
    const float* __restrict__ pool, int* __restrict__ mask) {
  __shared__ float row[NBLK];
  int h = blockIdx.x / NBLK, i = blockIdx.x % NBLK;
  int t = threadIdx.x;
  const float* pr = pool + ((long)h * NBLK + i) * NBLK;
  if (t < NBLK) row[t] = pr[t];
  __syncthreads();
  if (t < NBLK) {
    float pv = row[t];
    int rank = 0;
    for (int j = 0; j < NBLK; j++) {
      float o = row[j];
      rank += (o > pv) || (o == pv && j < t);
    }
    int val = 0;
    if (rank < 6) val = 1;
    else if (rank < 20) val = 2;
    else if (rank < 34) val = 4;
    else if (rank < 69) val = 8;
    if (t >= NBLK - 2) val = 1;
    if (i >= NBLK - 2) val = 1;
    mask[((long)h * NBLK + i) * NBLK + t] = val;
  }
}

// pooled K/V for levels m=2,4,8; compact 112 rows per (h, block)
__global__ __launch_bounds__(256) void k_poolkv(
    const float* __restrict__ kr, const float* __restrict__ vr,
    float* __restrict__ Kp, float* __restrict__ Vp) {
  long rid = (long)blockIdx.x * 4 + (threadIdx.x >> 6);
  int d = threadIdx.x & 63;
  const long total = 2L * NH * NBLK * 112;
  if (rid >= total) return;
  int tsel = (int)(rid / ((long)NH * NBLK * 112));
  long rem = rid - (long)tsel * NH * NBLK * 112;
  int h = (int)(rem / (NBLK * 112));
  int rem2 = (int)(rem % (NBLK * 112));
  int j = rem2 / 112, p = rem2 % 112;
  int m, g;
  if (p < 64) { m = 2; g = p; }
  else if (p < 96) { m = 4; g = p - 64; }
  else { m = 8; g = p - 96; }
  const float* src = tsel ? vr : kr;
  const float* base = src + ((long)h * LPAD + j * BLKSZ + g * m) * DD + d;
  float sum = 0.f;
  for (int r2 = 0; r2 < m; r2++) sum += base[(long)r2 * DD];
  float* dst = tsel ? Vp : Kp;
  dst[(((long)h * NBLK + j) * 112 + p) * DD + d] = sum / (float)m;
}

// ---------------- MFMA sparse attention ----------------
// Block: 256 threads = 4 waves; wave w owns q-rows [qi*128 + w*32, +32).
// KV stream: 16-row groups (raw or pooled), chunks of 2 groups (32 kv).
// S^T = K·Q^T via mfma(Kfrag, Qfrag); P stays in registers as the PV
// B-operand (kappa-invariance); O^T += mfma(V^T frag, P frag).
__global__ __launch_bounds__(256) void k_attn_mfma(
    const float* __restrict__ qr,
    const float* __restrict__ kr, const float* __restrict__ vr,
    const float* __restrict__ Kp, const float* __restrict__ Vp,
    const int* __restrict__ mask,
    float* __restrict__ outr) {
  __shared__ int glist[MAXG];
  __shared__ int ngarr[NBLK + 1];
  __shared__ short Kt[32 * 64];   // row-major, swizzled: s = r*64 + (d ^ ((r&7)<<3))
  __shared__ short Vt[64 * 32];   // transposed,  swizzled: s = d*32 + (r ^ ((d&7)<<2))
  __shared__ int smeta;

  int bid = blockIdx.x;
  int h = bid / NBLK;
  int qi = bid % NBLK;
  qi = (qi + NBLK - 2) % NBLK;   // heavy blocks (full-attn rows 137,138) first
  int tid = threadIdx.x;

  // ---- build 16-row group list ----
  int myng = 0, mylvl = 0, myG = 0;
  if (tid < NBLK) {
    int mv = mask[((long)h * NBLK + qi) * NBLK + tid];
    if (mv) {
      mylvl = (mv == 1) ? 0 : (mv == 2) ? 1 : (mv == 4) ? 2 : 3;
      myG = ((tid == NBLK - 1) ? VLAST : BLKSZ) >> mylvl;
      myng = (myG + 15) >> 4;
    }
    ngarr[tid] = myng;
  }
  __syncthreads();
  if (tid == 0) {
    int run = 0;
    for (int j = 0; j < NBLK; j++) { int t2 = ngarr[j]; ngarr[j] = run; run += t2; }
    int tot = run;
    if (tot & 1) { glist[tot] = 0; tot++; }   // dummy: src 0, cnt 0, raw
    smeta = tot >> 1;
  }
  __syncthreads();
  if (tid < NBLK && myng) {
    int off = ngarr[tid];
    int src0, pooled;
    if (mylvl == 0) { src0 = h * LPAD + tid * BLKSZ; pooled = 0; }
    else {
      int loff = (mylvl == 1) ? 0 : (mylvl == 2) ? 64 : 96;
      src0 = (h * NBLK + tid) * 112 + loff; pooled = 1;
    }
    for (int g = 0; g < myng; g++) {
      int cnt = myG - 16 * g; if (cnt > 16) cnt = 16;
      glist[off + g] = (src0 + 16 * g) | (cnt << 24) | (mylvl << 29) | (pooled << 31);
    }
  }

  int lane = tid & 63, wid = tid >> 6;
  int lm = lane & 15, lg = lane >> 4;

  // ---- Q fragments (held all kernel) ----
  short8v Qf[2][2];
#pragma unroll
  for (int mt = 0; mt < 2; mt++) {
#pragma unroll
    for (int ks = 0; ks < 2; ks++) {
      long row = (long)h * LPAD + qi * BLKSZ + wid * 32 + mt * 16 + lm;
      const float* qp = qr + row * DD + ks * 32 + lg * 8;
      float4 a = *(const float4*)qp;
      float4 b = *(const float4*)(qp + 4);
      short8v f;
      f[0] = (short)f2bf(a.x); f[1] = (short)f2bf(a.y);
      f[2] = (short)f2bf(a.z); f[3] = (short)f2bf(a.w);
      f[4] = (short)f2bf(b.x); f[5] = (short)f2bf(b.y);
      f[6] = (short)f2bf(b.z); f[7] = (short)f2bf(b.w);
      Qf[mt][ks] = f;
    }
  }

  f32x4 Oacc[4][2];
#pragma unroll
  for (int a = 0; a < 4; a++)
#pragma unroll
    for (int b = 0; b < 2; b++) {
      f32x4 z = {0.f, 0.f, 0.f, 0.f};
      Oacc[a][b] = z;
    }
  float lrow0 = 0.f, lrow1 = 0.f;

  __syncthreads();
  int nchunks = smeta;

  for (int c = 0; c < nchunks; c++) {
    __syncthreads();
    {  // ---- stage chunk: K row-major + V transposed, both swizzled ----
      int r = tid >> 3;            // kv row 0..31
      int d0 = (tid & 7) * 8;      // dim start
      unsigned ent = (unsigned)glist[2 * c + (r >> 4)];
      int src = (int)(ent & 0xFFFFFFu);
      const float* kbase = (ent >> 31) ? Kp : kr;
      const float* vbase = (ent >> 31) ? Vp : vr;
      long ro = ((long)(src + (r & 15))) * DD + d0;
      float4 ka = *(const float4*)(kbase + ro);
      float4 kb = *(const float4*)(kbase + ro + 4);
      float4 va = *(const float4*)(vbase + ro);
      float4 vb = *(const float4*)(vbase + ro + 4);
      short8v kf;
      kf[0] = (short)f2bf(ka.x); kf[1] = (short)f2bf(ka.y);
      kf[2] = (short)f2bf(ka.z); kf[3] = (short)f2bf(ka.w);
      kf[4] = (short)f2bf(kb.x); kf[5] = (short)f2bf(kb.y);
      kf[6] = (short)f2bf(kb.z); kf[7] = (short)f2bf(kb.w);
      *(short8v*)&Kt[r * 64 + (d0 ^ ((r & 7) << 3))] = kf;
      float vv[8] = {va.x, va.y, va.z, va.w, vb.x, vb.y, vb.z, vb.w};
#pragma unroll
      for (int i = 0; i < 8; i++)
        Vt[(d0 + i) * 32 + (r ^ (i << 2))] = (short)f2bf(vv[i]);
    }
    __syncthreads();

    unsigned e0 = (unsigned)glist[2 * c], e1 = (unsigned)glist[2 * c + 1];
    int cnt0 = (e0 >> 24) & 31, cnt1 = (e1 >> 24) & 31;
    float bias0 = (float)((e0 >> 29) & 3) * LN2F;
    float bias1 = (float)((e1 >> 29) & 3) * LN2F;

    short8v Kf[2][2];
#pragma unroll
    for (int nt = 0; nt < 2; nt++)
#pragma unroll
      for (int ks = 0; ks < 2; ks++) {
        int rowK = nt * 16 + lm;
        int dk = ks * 32 + lg * 8;
        Kf[nt][ks] = *(short8v*)&Kt[rowK * 64 + (dk ^ ((lm & 7) << 3))];
      }

    short8v Pf[2];
#pragma unroll
    for (int mt = 0; mt < 2; mt++) {
      f32x4 z = {0.f, 0.f, 0.f, 0.f};
      f32x4 a0 = __builtin_amdgcn_mfma_f32_16x16x32_bf16(Kf[0][0], Qf[mt][0], z, 0, 0, 0);
      a0 = __builtin_amdgcn_mfma_f32_16x16x32_bf16(Kf[0][1], Qf[mt][1], a0, 0, 0, 0);
      f32x4 a1 = __builtin_amdgcn_mfma_f32_16x16x32_bf16(Kf[1][0], Qf[mt][0], z, 0, 0, 0);
      a1 = __builtin_amdgcn_mfma_f32_16x16x32_bf16(Kf[1][1], Qf[mt][1], a1, 0, 0, 0);
      float lsum = 0.f;
      short8v pf;
#pragma unroll
      for (int i = 0; i < 4; i++) {
        int kvr = lg * 4 + i;
        float p0 = (kvr < cnt0) ? __expf(fmaf(a0[i], SCALE, bias0)) : 0.f;
        float p1 = (kvr < cnt1) ? __expf(fmaf(a1[i], SCALE, bias1)) : 0.f;
        unsigned short b0 = f2bf(p0), b1 = f2bf(p1);
        pf[i] = (short)b0; pf[4 + i] = (short)b1;
        lsum += bf2f(b0) + bf2f(b1);
      }
      Pf[mt] = pf;
      if (mt == 0) lrow0 += lsum; else lrow1 += lsum;
    }

#pragma unroll
    for (int mtp = 0; mtp < 4; mtp++) {
      int dV = mtp * 16 + lm;
      int c0 = lg * 4;
      int swz = (lm & 7) << 2;
      short4 lo = *(short4*)&Vt[dV * 32 + (c0 ^ swz)];
      short4 hi = *(short4*)&Vt[dV * 32 + ((16 + c0) ^ swz)];
      short8v vf;
      vf[0] = lo.x; vf[1] = lo.y; vf[2] = lo.z; vf[3] = lo.w;
      vf[4] = hi.x; vf[5] = hi.y; vf[6] = hi.z; vf[7] = hi.w;
      Oacc[mtp][0] = __builtin_amdgcn_mfma_f32_16x16x32_bf16(vf, Pf[0], Oacc[mtp][0], 0, 0, 0);
      Oacc[mtp][1] = __builtin_amdgcn_mfma_f32_16x16x32_bf16(vf, Pf[1], Oacc[mtp][1], 0, 0, 0);
    }
  }

  // ---- normalize + store ----
  lrow0 += __shfl_xor(lrow0, 16); lrow0 += __shfl_xor(lrow0, 32);
  lrow1 += __shfl_xor(lrow1, 16); lrow1 += __shfl_xor(lrow1, 32);
  float inv0 = 1.0f / lrow0, inv1 = 1.0f / lrow1;
#pragma unroll
  for (int mt = 0; mt < 2; mt++) {
    int grow = qi * BLKSZ + wid * 32 + mt * 16 + lm;
    if (grow >= LSEQ) continue;
    float inv = mt ? inv1 : inv0;
    float* orow = outr + ((long)h * LSEQ + grow) * DD;
#pragma unroll
    for (int mtp = 0; mtp < 4; mtp++) {
      f32x4 o = Oacc[mtp][mt];
      float4 st = make_float4(o[0] * inv, o[1] * inv, o[2] * inv, o[3] * inv);
      *(float4*)(orow + mtp * 16 + lg * 4) = st;
    }
  }
}

// final gather: out[h][r] = outr[h][outg[r]]
__global__ __launch_bounds__(256) void k_out(
    const float* __restrict__ outr, const int* __restrict__ outg,
    float* __restrict__ out) {
  long rid = (long)blockIdx.x * 4 + (threadIdx.x >> 6);
  int d = threadIdx.x & 63;
  const long total = (long)NH * LSEQ;
  if (rid >= total) return;
  int h = (int)(rid / LSEQ);
  int r = (int)(rid % LSEQ);
  int src = outg[r];
  out[((long)h * LSEQ + r) * DD + d] = outr[((long)h * LSEQ + src) * DD + d];
}

// ============================ launch ============================

extern "C" void kernel_launch(void* const* d_in, const int* in_sizes, int n_in,
                              void* d_out, int out_size, void* d_ws, size_t ws_size,
                              hipStream_t stream) {
  (void)in_sizes; (void)n_in; (void)out_size; (void)ws_size;
  const float* q = (const float*)d_in[0];
  const float* k = (const float*)d_in[1];
  const float* v = (const float*)d_in[2];
  float* ws = (float*)d_ws;
  float* out = (float*)d_out;

  static int* htab = nullptr;
  if (!htab) { (void)hipHostMalloc((void**)&htab, TAB_INTS * sizeof(int)); }
  build_tables(htab);

  int* dtab = (int*)(ws + F_TB);
  int* inmap = dtab;
  int* outg = dtab + LSEQ;
  int* qidx = dtab + 2 * LSEQ;
  int* kidx = qidx + NH * NKEEP;
  int* dmask = (int*)(ws + F_MK);
  float* qr = ws + F_QR; float* kr = ws + F_KR; float* vr = ws + F_VR;
  float* sq = ws + F_SQ; float* sk = ws + F_SK; float* pool = ws + F_PL;
  float* Kp = ws + F_KP; float* Vp = ws + F_VP;
  float* outr = ws + F_OR;

  hipMemcpyAsync(dtab, htab, TAB_INTS * sizeof(int), hipMemcpyHostToDevice, stream);

  {
    long rows = 3L * NH * LPAD;
    k_rearr<<<dim3((unsigned)((rows + 3) / 4)), 256, 0, stream>>>(q, k, v, qr, kr, vr, inmap);
  }
  {
    long rows = 2L * NH * NS;
    k_sample<<<dim3((unsigned)((rows + 3) / 4)), 256, 0, stream>>>(qr, kr, sq, sk, qidx, kidx);
  }
  k_scores_pool<<<dim3(NH * NBLK), 256, 0, stream>>>(sq, sk, pool);
  k_mask<<<dim3(NH * NBLK), 192, 0, stream>>>(pool, dmask);
  {
    long rows = 2L * NH * NBLK * 112;
    k_poolkv<<<dim3((unsigned)((rows + 3) / 4)), 256, 0, stream>>>(kr, vr, Kp, Vp);
  }
  k_attn_mfma<<<dim3(NH * NBLK), 256, 0, stream>>>(qr, kr, vr, Kp, Vp, dmask, outr);
  {
    long rows = (long)NH * LSEQ;
    k_out<<<dim3((unsigned)((rows + 3) / 4)), 256, 0, stream>>>(outr, outg, out);
  }
}

// Round 5
// 1090.330 us; speedup vs baseline: 10.9037x; 1.3126x over previous
//
#include <hip/hip_runtime.h>
#include <stdint.h>
#include <string.h>
#include <stdlib.h>

#define JAX_PARTITIONABLE 1

namespace {

constexpr int kW = 45, kH = 30, kD = 13;
constexpr int NVID = kW * kH * kD;          // 17550
constexpr int TEXT = 226;
constexpr int LSEQ = TEXT + NVID;           // 17776
constexpr int BLKSZ = 128;
constexpr int NBLK = 139;
constexpr int LPAD = NBLK * BLKSZ;          // 17792
constexpr int NKEEP = 32;
constexpr int NS = NBLK * NKEEP;            // 4448
constexpr int NH = 8;
constexpr int DD = 64;
constexpr int VLAST = LSEQ - (NBLK - 1) * BLKSZ;  // 112
constexpr float SCALE = 0.125f;
constexpr float LN2F = 0.69314718055994530942f;
constexpr int MAXG = 1116;                  // max 16-row groups (padded to x4)

// ---------------- workspace layout (float units) ----------------
constexpr long SZ_R  = (long)NH * LPAD * DD;        // 9109504 (fp32)
constexpr long SZ_RB = SZ_R / 2;                    // bf16 copy, in float units
constexpr long SZ_S  = (long)NH * NS * DD;          // 2277376
constexpr long SZ_PL = (long)NH * NBLK * NBLK;      // 154568
constexpr long SZ_KPB = (long)NH * NBLK * 112 * DD / 2;  // bf16, float units
constexpr long SZ_O  = (long)NH * LSEQ * DD;        // 9101312
constexpr long F_QR = 0;
constexpr long F_KR = F_QR + SZ_R;
constexpr long F_QB = F_KR + SZ_R;
constexpr long F_KB = F_QB + SZ_RB;
constexpr long F_VB = F_KB + SZ_RB;
constexpr long F_SQ = F_VB + SZ_RB;
constexpr long F_SK = F_SQ + SZ_S;
constexpr long F_PL = F_SK + SZ_S;
constexpr long F_KPB = F_PL + SZ_PL;
constexpr long F_VPB = F_KPB + SZ_KPB;
constexpr long F_MK = F_VPB + SZ_KPB;               // int32
constexpr long F_OR = F_MK + SZ_PL;
constexpr long F_TB = F_OR + SZ_O;                  // int32 tables
constexpr int TAB_INTS = 2 * LSEQ + 2 * NH * NKEEP;

// ============================ host: gilbert =============================
// Faithful port of the PROBLEM's _gen3d (volume-deficient regular-else branch
// included). o2g keeps trailing zeros; g2o keeps zeros for missed cells.
struct Gil { int* out; int n; };
static inline int sgn_i(int v) { return (v > 0) - (v < 0); }
static inline int fd2(int a) { return a >= 0 ? a / 2 : -((-a + 1) / 2); }

static void gen3d(Gil& G, int x, int y, int z,
                  int ax, int ay, int az,
                  int bx, int by, int bz,
                  int cx, int cy, int cz) {
  int w = abs(ax + ay + az), h = abs(bx + by + bz), d = abs(cx + cy + cz);
  int dax = sgn_i(ax), day = sgn_i(ay), daz = sgn_i(az);
  int dbx = sgn_i(bx), dby = sgn_i(by), dbz = sgn_i(bz);
  int dcx = sgn_i(cx), dcy = sgn_i(cy), dcz = sgn_i(cz);
  if (h == 1 && d == 1) { for (int i = 0; i < w; i++) { G.out[G.n++] = x + kW * (y + kH * z); x += dax; y += day; z += daz; } return; }
  if (w == 1 && d == 1) { for (int i = 0; i < h; i++) { G.out[G.n++] = x + kW * (y + kH * z); x += dbx; y += dby; z += dbz; } return; }
  if (w == 1 && h == 1) { for (int i = 0; i < d; i++) { G.out[G.n++] = x + kW * (y + kH * z); x += dcx; y += dcy; z += dcz; } return; }
  int ax2 = fd2(ax), ay2 = fd2(ay), az2 = fd2(az);
  int bx2 = fd2(bx), by2 = fd2(by), bz2 = fd2(bz);
  int cx2 = fd2(cx), cy2 = fd2(cy), cz2 = fd2(cz);
  int w2 = abs(ax2 + ay2 + az2), h2 = abs(bx2 + by2 + bz2), d2 = abs(cx2 + cy2 + cz2);
  if ((w2 & 1) && w > 2) { ax2 += dax; ay2 += day; az2 += daz; }
  if ((h2 & 1) && h > 2) { bx2 += dbx; by2 += dby; bz2 += dbz; }
  if ((d2 & 1) && d > 2) { cx2 += dcx; cy2 += dcy; cz2 += dcz; }
  if (2 * w > 3 * h && 2 * w > 3 * d) {
    gen3d(G, x, y, z, ax2, ay2, az2, bx, by, bz, cx, cy, cz);
    gen3d(G, x + ax2, y + ay2, z + az2, ax - ax2, ay - ay2, az - az2, bx, by, bz, cx, cy, cz);
  } else if (3 * h > 4 * d) {
    gen3d(G, x, y, z, bx2, by2, bz2, cx, cy, cz, ax2, ay2, az2);
    gen3d(G, x + bx2, y + by2, z + bz2, ax, ay, az, bx - bx2, by - by2, bz - bz2, cx, cy, cz);
    gen3d(G, x + (ax - dax) + (bx2 - dbx), y + (ay - day) + (by2 - dby), z + (az - daz) + (bz2 - dbz),
          -bx2, -by2, -bz2, cx, cy, cz, -(ax - ax2), -(ay - ay2), -(az - az2));
  } else if (3 * d > 4 * h) {
    gen3d(G, x, y, z, cx2, cy2, cz2, ax2, ay2, az2, bx, by, bz);
    gen3d(G, x + cx2, y + cy2, z + cz2, ax, ay, az, bx, by, bz, cx - cx2, cy - cy2, cz - cz2);
    gen3d(G, x + (ax - dax) + (cx2 - dcx), y + (ay - day) + (cy2 - dcy), z + (az - daz) + (cz2 - dcz),
          -cx2, -cy2, -cz2, -(ax - ax2), -(ay - ay2), -(az - az2), bx, by, bz);
  } else {
    gen3d(G, x, y, z, bx2, by2, bz2, cx2, cy2, cz2, ax2, ay2, az2);
    gen3d(G, x + bx2, y + by2, z + bz2, cx, cy, cz, ax2, ay2, az2, bx - bx2, by - by2, bz - bz2);
    gen3d(G, x + (bx2 - dbx) + (cx - dcx), y + (by2 - dby) + (cy - dcy), z + (bz2 - dbz) + (cz - dcz),
          ax, ay, az, -bx2, -by2, -bz2, -(cx - cx2), -(cy - cy2), -(cz - cz2));
    gen3d(G, x + (ax - dax) + bx2 + (cx - dcx), y + (ay - day) + by2 + (cy - dcy), z + (az - daz) + bz2 + (cz - dcz),
          -cx, -cy, -cz, -(ax - ax2), -(ay - ay2), -(az - az2), bx - bx2, by - by2, bz - bz2);
  }
}

// ============================ host: threefry ============================
static void tf2x32(uint32_t k0, uint32_t k1, uint32_t x0, uint32_t x1,
                   uint32_t& o0, uint32_t& o1) {
  uint32_t ks0 = k0, ks1 = k1, ks2 = k0 ^ k1 ^ 0x1BD11BDAu;
  const uint32_t ks[3] = {ks0, ks1, ks2};
  const int rot[2][4] = {{13, 15, 26, 6}, {17, 29, 16, 24}};
  x0 += ks[0]; x1 += ks[1];
  for (int i = 0; i < 5; i++) {
    for (int j = 0; j < 4; j++) {
      int rr = rot[i & 1][j];
      x0 += x1;
      x1 = (x1 << rr) | (x1 >> (32 - rr));
      x1 ^= x0;
    }
    x0 += ks[(i + 1) % 3];
    x1 += ks[(i + 2) % 3] + (uint32_t)(i + 1);
  }
  o0 = x0; o1 = x1;
}

static inline float bits_to_unit(uint32_t bits) {
  uint32_t fb = (bits >> 9) | 0x3f800000u;
  float f; memcpy(&f, &fb, 4);
  return f - 1.0f;
}

static void fill_idx(uint32_t K0, uint32_t K1, int* dst) {
  float u[NH * BLKSZ];
#if JAX_PARTITIONABLE
  for (int i = 0; i < NH * BLKSZ; i++) {
    uint32_t a, b; tf2x32(K0, K1, 0u, (uint32_t)i, a, b);
    u[i] = bits_to_unit(a ^ b);
  }
#else
  {
    const int n = NH * BLKSZ, hn = n / 2;
    for (int i = 0; i < hn; i++) {
      uint32_t a, b; tf2x32(K0, K1, (uint32_t)i, (uint32_t)(hn + i), a, b);
      u[i] = bits_to_unit(a);
      u[hn + i] = bits_to_unit(b);
    }
  }
#endif
  for (int h = 0; h < NH; h++) {
    const float* row = u + h * BLKSZ;
    bool used[BLKSZ] = {false};
    for (int r = 0; r < NKEEP; r++) {
      int best = -1; float bv = -2.0f;
      for (int g = 0; g < BLKSZ; g++)
        if (!used[g] && row[g] > bv) { bv = row[g]; best = g; }
      used[best] = true;
      dst[h * NKEEP + r] = best;
    }
  }
}

static void build_tables(int* tab) {
  static int yields[NVID];
  static int o2g_buf[NVID];
  static int g2o_buf[NVID];
  memset(o2g_buf, 0, sizeof(o2g_buf));
  memset(g2o_buf, 0, sizeof(g2o_buf));
  Gil G{yields, 0};
  gen3d(G, 0, 0, 0, kW, 0, 0, 0, kH, 0, 0, 0, kD);
  int n = G.n;
  if (n > NVID) n = NVID;
  for (int g = 0; g < n; g++) o2g_buf[g] = yields[g];
  for (int g = 0; g < n; g++) g2o_buf[yields[g]] = g;

  int* inmap = tab;
  int* outg  = tab + LSEQ;
  for (int g = 0; g < NVID; g++) inmap[g] = TEXT + o2g_buf[g];
  for (int t = 0; t < TEXT; t++) inmap[NVID + t] = t;
  for (int r = 0; r < TEXT; r++) outg[r] = NVID + r;
  for (int c = 0; c < NVID; c++) outg[TEXT + c] = g2o_buf[c];

  uint32_t kq0, kq1, kk0, kk1;
#if JAX_PARTITIONABLE
  tf2x32(0, 0, 0, 0, kq0, kq1);
  tf2x32(0, 0, 0, 1, kk0, kk1);
#else
  {
    uint32_t y00, y10, y01, y11;
    tf2x32(0, 0, 0, 2, y00, y10);
    tf2x32(0, 0, 1, 3, y01, y11);
    kq0 = y00; kq1 = y01; kk0 = y10; kk1 = y11;
  }
#endif
  fill_idx(kq0, kq1, tab + 2 * LSEQ);
  fill_idx(kk0, kk1, tab + 2 * LSEQ + NH * NKEEP);
}

}  // namespace

// ============================ device helpers ============================

typedef __attribute__((ext_vector_type(8))) short short8v;
typedef __attribute__((ext_vector_type(4))) float f32x4;

static __device__ inline unsigned short f2bf(float f) {
  unsigned u = __float_as_uint(f);
  unsigned r = u + 0x7FFFu + ((u >> 16) & 1u);  // RNE
  return (unsigned short)(r >> 16);
}
static __device__ inline float bf2f(unsigned short s) {
  return __uint_as_float(((unsigned)s) << 16);
}

// ============================ device kernels ============================

// rearrange; fp32 q/k for the mask path, bf16 q/k/v for the attention path
__global__ __launch_bounds__(256) void k_rearr(
    const float* __restrict__ q, const float* __restrict__ k, const float* __restrict__ v,
    float* __restrict__ qr, float* __restrict__ kr,
    short* __restrict__ qrb, short* __restrict__ krb, short* __restrict__ vrb,
    const int* __restrict__ inmap) {
  long rid = (long)blockIdx.x * 4 + (threadIdx.x >> 6);
  int d = threadIdx.x & 63;
  const long total = 3L * NH * LPAD;
  if (rid >= total) return;
  int tsel = (int)(rid / ((long)NH * LPAD));
  long rem = rid - (long)tsel * NH * LPAD;
  int h = (int)(rem / LPAD);
  int i = (int)(rem % LPAD);
  const float* src = tsel == 0 ? q : (tsel == 1 ? k : v);
  float val = 0.f;
  if (i < LSEQ) val = src[((long)h * LSEQ + inmap[i]) * DD + d];
  long o = ((long)h * LPAD + i) * DD + d;
  if (tsel == 0) { qr[o] = val; qrb[o] = (short)f2bf(val); }
  else if (tsel == 1) { kr[o] = val; krb[o] = (short)f2bf(val); }
  else { vrb[o] = (short)f2bf(val); }
}

__global__ __launch_bounds__(256) void k_sample(
    const float* __restrict__ qr, const float* __restrict__ kr,
    float* __restrict__ sq, float* __restrict__ sk,
    const int* __restrict__ qidx, const int* __restrict__ kidx) {
  long rid = (long)blockIdx.x * 4 + (threadIdx.x >> 6);
  int d = threadIdx.x & 63;
  const long total = 2L * NH * NS;
  if (rid >= total) return;
  int tsel = (int)(rid / ((long)NH * NS));
  long rem = rid - (long)tsel * NH * NS;
  int h = (int)(rem / NS);
  int s = (int)(rem % NS);
  int b = s / NKEEP, t = s % NKEEP;
  const int* idx = tsel ? kidx : qidx;
  int p = b * BLKSZ + idx[h * NKEEP + t];
  if (p >= LSEQ) p = LSEQ - 1;
  const float* src = tsel ? kr : qr;
  float* dst = tsel ? sk : sq;
  dst[((long)h * NS + s) * DD + d] = src[((long)h * LPAD + p) * DD + d];
}

__global__ __launch_bounds__(256) void k_scores_pool(
    const float* __restrict__ sq, const float* __restrict__ sk, float* __restrict__ pool) {
  __shared__ float kt[NKEEP * DD];
  __shared__ float bins[NKEEP * NBLK];
  __shared__ float bpart[4][NKEEP];
  __shared__ float invden[NKEEP];
  int h = blockIdx.x / NBLK, qb = blockIdx.x % NBLK;
  int t = threadIdx.x;
  int r = t & 31;
  int c = t >> 5;
  float4 qv[16];
  {
    const float4* q4 = (const float4*)(sq + ((long)h * NS + qb * NKEEP + r) * DD);
#pragma unroll
    for (int i = 0; i < 16; i++) qv[i] = q4[i];
  }
  for (int i = t; i < NKEEP * NBLK; i += 256) bins[i] = 0.f;
  const float* skh = sk + (long)h * NS * DD;
  for (int kb = 0; kb < NBLK; kb++) {
    __syncthreads();
    const float4* src4 = (const float4*)(skh + (long)kb * NKEEP * DD);
    for (int i = t; i < NKEEP * DD / 4; i += 256) ((float4*)kt)[i] = src4[i];
    __syncthreads();
    float acc = 0.f;
#pragma unroll
    for (int i = 0; i < 4; i++) {
      int krow = c * 4 + i;
      const float4* k4 = (const float4*)(kt + krow * DD);
      float s = 0.f;
#pragma unroll
      for (int d4 = 0; d4 < 16; d4++) {
        float4 a = qv[d4], b = k4[d4];
        s += a.x * b.x + a.y * b.y + a.z * b.z + a.w * b.w;
      }
      acc += __expf(s * SCALE);
    }
    acc += __shfl_xor(acc, 32);
    if ((t & 32) == 0) bpart[t >> 6][r] = acc;
    __syncthreads();
    if (t < NKEEP) bins[t * NBLK + kb] = bpart[0][t] + bpart[1][t] + bpart[2][t] + bpart[3][t];
  }
  __syncthreads();
  if (t < NKEEP) {
    float s = 0.f;
    for (int kb = 0; kb < NBLK; kb++) s += bins[t * NBLK + kb];
    invden[t] = 1.0f / s;
  }
  __syncthreads();
  if (t < NBLK) {
    float s = 0.f;
    for (int r2 = 0; r2 < NKEEP; r2++) s += bins[r2 * NBLK + t] * invden[r2];
    pool[((long)h * NBLK + qb) * NBLK + t] = s;
  }
}

__global__ __launch_bounds__(192) void k_mask(
    const float* __restrict__ pool, int* __restrict__ mask) {
  __shared__ float row[NBLK];
  int h = blockIdx.x / NBLK, i = blockIdx.x % NBLK;
  int t = threadIdx.x;
  const float* pr = pool + ((long)h * NBLK + i) * NBLK;
  if (t < NBLK) row[t] = pr[t];
  __syncthreads();
  if (t < NBLK) {
    float pv = row[t];
    int rank = 0;
    for (int j = 0; j < NBLK; j++) {
      float o = row[j];
      rank += (o > pv) || (o == pv && j < t);
    }
    int val = 0;
    if (rank < 6) val = 1;
    else if (rank < 20) val = 2;
    else if (rank < 34) val = 4;
    else if (rank < 69) val = 8;
    if (t >= NBLK - 2) val = 1;
    if (i >= NBLK - 2) val = 1;
    mask[((long)h * NBLK + i) * NBLK + t] = val;
  }
}

// pooled K/V from bf16, output bf16; 112 compact rows per (h, block)
__global__ __launch_bounds__(256) void k_poolkv(
    const short* __restrict__ krb, const short* __restrict__ vrb,
    short* __restrict__ Kpb, short* __restrict__ Vpb) {
  long rid = (long)blockIdx.x * 4 + (threadIdx.x >> 6);
  int d = threadIdx.x & 63;
  const long total = 2L * NH * NBLK * 112;
  if (rid >= total) return;
  int tsel = (int)(rid / ((long)NH * NBLK * 112));
  long rem = rid - (long)tsel * NH * NBLK * 112;
  int h = (int)(rem / (NBLK * 112));
  int rem2 = (int)(rem % (NBLK * 112));
  int j = rem2 / 112, p = rem2 % 112;
  int m, g;
  if (p < 64) { m = 2; g = p; }
  else if (p < 96) { m = 4; g = p - 64; }
  else { m = 8; g = p - 96; }
  const short* src = tsel ? vrb : krb;
  const short* base = src + ((long)h * LPAD + j * BLKSZ + g * m) * DD + d;
  float sum = 0.f;
  for (int r2 = 0; r2 < m; r2++) sum += bf2f((unsigned short)base[(long)r2 * DD]);
  short* dst = tsel ? Vpb : Kpb;
  dst[(((long)h * NBLK + j) * 112 + p) * DD + d] = (short)f2bf(sum / (float)m);
}

// ---------------- MFMA sparse attention, 64-kv chunks, prefetched ----------------
__global__ __launch_bounds__(256) void k_attn_mfma(
    const short* __restrict__ qrb, const short* __restrict__ krb,
    const short* __restrict__ vrb,
    const short* __restrict__ Kpb, const short* __restrict__ Vpb,
    const int* __restrict__ mask,
    float* __restrict__ outr) {
  __shared__ int glist[MAXG];
  __shared__ int ngarr[NBLK + 1];
  __shared__ __align__(16) short Kt[64 * 64];   // swizzled row-major
  __shared__ __align__(16) short Vt[64 * 68];   // V^T [d][kv], stride 68
  __shared__ int smeta;

  int bid = blockIdx.x;
  int h = bid / NBLK;
  int qi = bid % NBLK;
  qi = (qi + NBLK - 2) % NBLK;   // heavy blocks first
  int tid = threadIdx.x;

  // ---- group list ----
  int myng = 0, mylvl = 0, myG = 0;
  if (tid < NBLK) {
    int mv = mask[((long)h * NBLK + qi) * NBLK + tid];
    if (mv) {
      mylvl = (mv == 1) ? 0 : (mv == 2) ? 1 : (mv == 4) ? 2 : 3;
      myG = ((tid == NBLK - 1) ? VLAST : BLKSZ) >> mylvl;
      myng = (myG + 15) >> 4;
    }
    ngarr[tid] = myng;
  }
  __syncthreads();
  if (tid == 0) {
    int run = 0;
    for (int j = 0; j < NBLK; j++) { int t2 = ngarr[j]; ngarr[j] = run; run += t2; }
    int tot = run;
    while (tot & 3) glist[tot++] = 0;   // dummy pads (src 0, cnt 0)
    smeta = tot >> 2;
  }
  __syncthreads();
  if (tid < NBLK && myng) {
    int off = ngarr[tid];
    int src0, pooled;
    if (mylvl == 0) { src0 = h * LPAD + tid * BLKSZ; pooled = 0; }
    else {
      int loff = (mylvl == 1) ? 0 : (mylvl == 2) ? 64 : 96;
      src0 = (h * NBLK + tid) * 112 + loff; pooled = 1;
    }
    for (int g = 0; g < myng; g++) {
      int cnt = myG - 16 * g; if (cnt > 16) cnt = 16;
      glist[off + g] = (src0 + 16 * g) | (cnt << 24) | (mylvl << 29) | (pooled << 31);
    }
  }

  int lane = tid & 63, wid = tid >> 6;
  int lm = lane & 15, lg = lane >> 4;

  // ---- Q fragments ----
  short8v Qf[2][2];
#pragma unroll
  for (int mt = 0; mt < 2; mt++)
#pragma unroll
    for (int ks = 0; ks < 2; ks++) {
      long row = (long)h * LPAD + qi * BLKSZ + wid * 32 + mt * 16 + lm;
      Qf[mt][ks] = *(const short8v*)(qrb + row * DD + ks * 32 + lg * 8);
    }

  f32x4 Oacc[4][2];
#pragma unroll
  for (int a = 0; a < 4; a++)
#pragma unroll
    for (int b = 0; b < 2; b++) { f32x4 z = {0.f, 0.f, 0.f, 0.f}; Oacc[a][b] = z; }
  float lrow0 = 0.f, lrow1 = 0.f;

  __syncthreads();
  int nchunks = smeta;

  // staging thread map: row r = tid&63, dims d0 = (tid>>6)*16 + {0,8}
  int sr = tid & 63;
  int sd0 = (tid >> 6) * 16;

  short8v pkA, pkB, pvA, pvB;
  {  // prologue: load chunk 0
    unsigned ent = (unsigned)glist[(sr >> 4)];
    long src = (long)((ent & 0xFFFFFFu) + (sr & 15));
    const short* kb = (ent >> 31) ? Kpb : krb;
    const short* vb = (ent >> 31) ? Vpb : vrb;
    const short8v* kp = (const short8v*)(kb + src * DD + sd0);
    const short8v* vp = (const short8v*)(vb + src * DD + sd0);
    pkA = kp[0]; pkB = kp[1];
    pvA = vp[0]; pvB = vp[1];
  }

  for (int c = 0; c < nchunks; c++) {
    __syncthreads();   // previous chunk's LDS reads complete
    // ---- stage chunk c from regs ----
    {
      int sw = (sr & 7) << 3;
      *(short8v*)&Kt[sr * 64 + (sd0 ^ sw)] = pkA;
      *(short8v*)&Kt[sr * 64 + ((sd0 + 8) ^ sw)] = pkB;
#pragma unroll
      for (int i = 0; i < 8; i++) {
        Vt[(sd0 + i) * 68 + sr] = pvA[i];
        Vt[(sd0 + 8 + i) * 68 + sr] = pvB[i];
      }
    }
    __syncthreads();
    // ---- issue prefetch for chunk c+1 ----
    if (c + 1 < nchunks) {
      unsigned ent = (unsigned)glist[4 * (c + 1) + (sr >> 4)];
      long src = (long)((ent & 0xFFFFFFu) + (sr & 15));
      const short* kb = (ent >> 31) ? Kpb : krb;
      const short* vb = (ent >> 31) ? Vpb : vrb;
      const short8v* kp = (const short8v*)(kb + src * DD + sd0);
      const short8v* vp = (const short8v*)(vb + src * DD + sd0);
      pkA = kp[0]; pkB = kp[1];
      pvA = vp[0]; pvB = vp[1];
    }

    // ---- metadata ----
    int cntv[4]; float biasv[4];
#pragma unroll
    for (int g = 0; g < 4; g++) {
      unsigned e = (unsigned)glist[4 * c + g];
      cntv[g] = (e >> 24) & 31;
      biasv[g] = (float)((e >> 29) & 3) * LN2F;
    }

    // ---- K frags + S^T ----
    short8v Kf[4][2];
#pragma unroll
    for (int nt = 0; nt < 4; nt++)
#pragma unroll
      for (int ks = 0; ks < 2; ks++)
        Kf[nt][ks] = *(short8v*)&Kt[(nt * 16 + lm) * 64 + ((ks * 32 + lg * 8) ^ ((lm & 7) << 3))];

    f32x4 aq[2][4];
#pragma unroll
    for (int mt = 0; mt < 2; mt++)
#pragma unroll
      for (int nt = 0; nt < 4; nt++) {
        f32x4 z = {0.f, 0.f, 0.f, 0.f};
        f32x4 a = __builtin_amdgcn_mfma_f32_16x16x32_bf16(Kf[nt][0], Qf[mt][0], z, 0, 0, 0);
        aq[mt][nt] = __builtin_amdgcn_mfma_f32_16x16x32_bf16(Kf[nt][1], Qf[mt][1], a, 0, 0, 0);
      }

    // ---- softmax -> P frags ----
    short8v Pf[2][2];
#pragma unroll
    for (int mt = 0; mt < 2; mt++) {
      float lsum = 0.f;
#pragma unroll
      for (int H = 0; H < 2; H++) {
        short8v pf;
#pragma unroll
        for (int g2 = 0; g2 < 2; g2++) {
          int nt = 2 * H + g2;
          int cnt = cntv[nt]; float bias = biasv[nt];
#pragma unroll
          for (int i = 0; i < 4; i++) {
            int kvr = lg * 4 + i;
            float p = (kvr < cnt) ? __expf(fmaf(aq[mt][nt][i], SCALE, bias)) : 0.f;
            unsigned short b = f2bf(p);
            pf[g2 * 4 + i] = (short)b;
            lsum += bf2f(b);
          }
        }
        Pf[mt][H] = pf;
      }
      if (mt == 0) lrow0 += lsum; else lrow1 += lsum;
    }

    // ---- PV ----
#pragma unroll
    for (int mtp = 0; mtp < 4; mtp++) {
      int d68 = (mtp * 16 + lm) * 68;
#pragma unroll
      for (int H = 0; H < 2; H++) {
        short4 lo = *(short4*)&Vt[d68 + H * 32 + lg * 4];
        short4 hi = *(short4*)&Vt[d68 + H * 32 + 16 + lg * 4];
        short8v vf;
        vf[0] = lo.x; vf[1] = lo.y; vf[2] = lo.z; vf[3] = lo.w;
        vf[4] = hi.x; vf[5] = hi.y; vf[6] = hi.z; vf[7] = hi.w;
        Oacc[mtp][0] = __builtin_amdgcn_mfma_f32_16x16x32_bf16(vf, Pf[0][H], Oacc[mtp][0], 0, 0, 0);
        Oacc[mtp][1] = __builtin_amdgcn_mfma_f32_16x16x32_bf16(vf, Pf[1][H], Oacc[mtp][1], 0, 0, 0);
      }
    }
  }

  // ---- normalize + store ----
  lrow0 += __shfl_xor(lrow0, 16); lrow0 += __shfl_xor(lrow0, 32);
  lrow1 += __shfl_xor(lrow1, 16); lrow1 += __shfl_xor(lrow1, 32);
  float inv0 = 1.0f / lrow0, inv1 = 1.0f / lrow1;
#pragma unroll
  for (int mt = 0; mt < 2; mt++) {
    int grow = qi * BLKSZ + wid * 32 + mt * 16 + lm;
    if (grow >= LSEQ) continue;
    float inv = mt ? inv1 : inv0;
    float* orow = outr + ((long)h * LSEQ + grow) * DD;
#pragma unroll
    for (int mtp = 0; mtp < 4; mtp++) {
      f32x4 o = Oacc[mtp][mt];
      float4 st = make_float4(o[0] * inv, o[1] * inv, o[2] * inv, o[3] * inv);
      *(float4*)(orow + mtp * 16 + lg * 4) = st;
    }
  }
}

// final gather
__global__ __launch_bounds__(256) void k_out(
    const float* __restrict__ outr, const int* __restrict__ outg,
    float* __restrict__ out) {
  long rid = (long)blockIdx.x * 4 + (threadIdx.x >> 6);
  int d = threadIdx.x & 63;
  const long total = (long)NH * LSEQ;
  if (rid >= total) return;
  int h = (int)(rid / LSEQ);
  int r = (int)(rid % LSEQ);
  int src = outg[r];
  out[((long)h * LSEQ + r) * DD + d] = outr[((long)h * LSEQ + src) * DD + d];
}

// ============================ launch ============================

extern "C" void kernel_launch(void* const* d_in, const int* in_sizes, int n_in,
                              void* d_out, int out_size, void* d_ws, size_t ws_size,
                              hipStream_t stream) {
  (void)in_sizes; (void)n_in; (void)out_size; (void)ws_size;
  const float* q = (const float*)d_in[0];
  const float* k = (const float*)d_in[1];
  const float* v = (const float*)d_in[2];
  float* ws = (float*)d_ws;
  float* out = (float*)d_out;

  static int* htab = nullptr;
  if (!htab) { (void)hipHostMalloc((void**)&htab, TAB_INTS * sizeof(int)); }
  build_tables(htab);

  int* dtab = (int*)(ws + F_TB);
  int* inmap = dtab;
  int* outg = dtab + LSEQ;
  int* qidx = dtab + 2 * LSEQ;
  int* kidx = qidx + NH * NKEEP;
  int* dmask = (int*)(ws + F_MK);
  float* qr = ws + F_QR; float* kr = ws + F_KR;
  short* qrb = (short*)(ws + F_QB);
  short* krb = (short*)(ws + F_KB);
  short* vrb = (short*)(ws + F_VB);
  float* sq = ws + F_SQ; float* sk = ws + F_SK; float* pool = ws + F_PL;
  short* Kpb = (short*)(ws + F_KPB);
  short* Vpb = (short*)(ws + F_VPB);
  float* outr = ws + F_OR;

  hipMemcpyAsync(dtab, htab, TAB_INTS * sizeof(int), hipMemcpyHostToDevice, stream);

  {
    long rows = 3L * NH * LPAD;
    k_rearr<<<dim3((unsigned)((rows + 3) / 4)), 256, 0, stream>>>(
        q, k, v, qr, kr, qrb, krb, vrb, inmap);
  }
  {
    long rows = 2L * NH * NS;
    k_sample<<<dim3((unsigned)((rows + 3) / 4)), 256, 0, stream>>>(qr, kr, sq, sk, qidx, kidx);
  }
  k_scores_pool<<<dim3(NH * NBLK), 256, 0, stream>>>(sq, sk, pool);
  k_mask<<<dim3(NH * NBLK), 192, 0, stream>>>(pool, dmask);
  {
    long rows = 2L * NH * NBLK * 112;
    k_poolkv<<<dim3((unsigned)((rows + 3) / 4)), 256, 0, stream>>>(krb, vrb, Kpb, Vpb);
  }
  k_attn_mfma<<<dim3(NH * NBLK), 256, 0, stream>>>(qrb, krb, vrb, Kpb, Vpb, dmask, outr);
  {
    long rows = (long)NH * LSEQ;
    k_out<<<dim3((unsigned)((rows + 3) / 4)), 256, 0, stream>>>(outr, outg, out);
  }
}

// Round 6
// 1080.227 us; speedup vs baseline: 11.0056x; 1.0094x over previous
//
#include <hip/hip_runtime.h>
#include <stdint.h>
#include <string.h>
#include <stdlib.h>

#define JAX_PARTITIONABLE 1

namespace {

constexpr int kW = 45, kH = 30, kD = 13;
constexpr int NVID = kW * kH * kD;          // 17550
constexpr int TEXT = 226;
constexpr int LSEQ = TEXT + NVID;           // 17776
constexpr int BLKSZ = 128;
constexpr int NBLK = 139;
constexpr int LPAD = NBLK * BLKSZ;          // 17792
constexpr int NKEEP = 32;
constexpr int NS = NBLK * NKEEP;            // 4448
constexpr int NH = 8;
constexpr int DD = 64;
constexpr int VLAST = LSEQ - (NBLK - 1) * BLKSZ;  // 112
constexpr float SCALE = 0.125f;
constexpr float LN2F = 0.69314718055994530942f;
constexpr int MAXG = 188;                   // light rows: <=182 groups (+pad)

// heavy split
constexpr int NSPLIT = 8;
constexpr int HCHUNK = (LSEQ + 63) / 64;    // 278 chunks of 64 kv
constexpr int CHPER = (HCHUNK + NSPLIT - 1) / NSPLIT;  // 35
constexpr int NHEAVYB = NH * 2 * NSPLIT;    // 128 blocks
constexpr int NLIGHT = NH * (NBLK - 2);     // 1096

// ---------------- workspace layout (float units) ----------------
constexpr long SZ_R  = (long)NH * LPAD * DD;        // fp32
constexpr long SZ_RB = SZ_R / 2;                    // bf16, float units
constexpr long SZ_S  = (long)NH * NS * DD;
constexpr long SZ_PL = (long)NH * NBLK * NBLK;
constexpr long SZ_KPB = (long)NH * NBLK * 112 * DD / 2;
constexpr long SZ_O  = (long)NH * LSEQ * DD;
constexpr long SZ_PT = (long)NH * 2 * NSPLIT * BLKSZ * DD;  // heavy partials
constexpr long SZ_PS = (long)NH * 2 * NSPLIT * BLKSZ;       // heavy lsums
constexpr long F_QR = 0;
constexpr long F_KR = F_QR + SZ_R;
constexpr long F_QB = F_KR + SZ_R;
constexpr long F_KB = F_QB + SZ_RB;
constexpr long F_VB = F_KB + SZ_RB;
constexpr long F_SQ = F_VB + SZ_RB;
constexpr long F_SK = F_SQ + SZ_S;
constexpr long F_PL = F_SK + SZ_S;
constexpr long F_KPB = F_PL + SZ_PL;
constexpr long F_VPB = F_KPB + SZ_KPB;
constexpr long F_MK = F_VPB + SZ_KPB;               // int32
constexpr long F_OR = F_MK + SZ_PL;
constexpr long F_PT = F_OR + SZ_O;
constexpr long F_PS = F_PT + SZ_PT;
constexpr long F_TB = F_PS + SZ_PS;                 // int32 tables
constexpr int TAB_INTS = 2 * LSEQ + 2 * NH * NKEEP;

// ============================ host: gilbert =============================
// Faithful port of the PROBLEM's _gen3d (volume-deficient regular-else branch
// included). o2g keeps trailing zeros; g2o keeps zeros for missed cells.
struct Gil { int* out; int n; };
static inline int sgn_i(int v) { return (v > 0) - (v < 0); }
static inline int fd2(int a) { return a >= 0 ? a / 2 : -((-a + 1) / 2); }

static void gen3d(Gil& G, int x, int y, int z,
                  int ax, int ay, int az,
                  int bx, int by, int bz,
                  int cx, int cy, int cz) {
  int w = abs(ax + ay + az), h = abs(bx + by + bz), d = abs(cx + cy + cz);
  int dax = sgn_i(ax), day = sgn_i(ay), daz = sgn_i(az);
  int dbx = sgn_i(bx), dby = sgn_i(by), dbz = sgn_i(bz);
  int dcx = sgn_i(cx), dcy = sgn_i(cy), dcz = sgn_i(cz);
  if (h == 1 && d == 1) { for (int i = 0; i < w; i++) { G.out[G.n++] = x + kW * (y + kH * z); x += dax; y += day; z += daz; } return; }
  if (w == 1 && d == 1) { for (int i = 0; i < h; i++) { G.out[G.n++] = x + kW * (y + kH * z); x += dbx; y += dby; z += dbz; } return; }
  if (w == 1 && h == 1) { for (int i = 0; i < d; i++) { G.out[G.n++] = x + kW * (y + kH * z); x += dcx; y += dcy; z += dcz; } return; }
  int ax2 = fd2(ax), ay2 = fd2(ay), az2 = fd2(az);
  int bx2 = fd2(bx), by2 = fd2(by), bz2 = fd2(bz);
  int cx2 = fd2(cx), cy2 = fd2(cy), cz2 = fd2(cz);
  int w2 = abs(ax2 + ay2 + az2), h2 = abs(bx2 + by2 + bz2), d2 = abs(cx2 + cy2 + cz2);
  if ((w2 & 1) && w > 2) { ax2 += dax; ay2 += day; az2 += daz; }
  if ((h2 & 1) && h > 2) { bx2 += dbx; by2 += dby; bz2 += dbz; }
  if ((d2 & 1) && d > 2) { cx2 += dcx; cy2 += dcy; cz2 += dcz; }
  if (2 * w > 3 * h && 2 * w > 3 * d) {
    gen3d(G, x, y, z, ax2, ay2, az2, bx, by, bz, cx, cy, cz);
    gen3d(G, x + ax2, y + ay2, z + az2, ax - ax2, ay - ay2, az - az2, bx, by, bz, cx, cy, cz);
  } else if (3 * h > 4 * d) {
    gen3d(G, x, y, z, bx2, by2, bz2, cx, cy, cz, ax2, ay2, az2);
    gen3d(G, x + bx2, y + by2, z + bz2, ax, ay, az, bx - bx2, by - by2, bz - bz2, cx, cy, cz);
    gen3d(G, x + (ax - dax) + (bx2 - dbx), y + (ay - day) + (by2 - dby), z + (az - daz) + (bz2 - dbz),
          -bx2, -by2, -bz2, cx, cy, cz, -(ax - ax2), -(ay - ay2), -(az - az2));
  } else if (3 * d > 4 * h) {
    gen3d(G, x, y, z, cx2, cy2, cz2, ax2, ay2, az2, bx, by, bz);
    gen3d(G, x + cx2, y + cy2, z + cz2, ax, ay, az, bx, by, bz, cx - cx2, cy - cy2, cz - cz2);
    gen3d(G, x + (ax - dax) + (cx2 - dcx), y + (ay - day) + (cy2 - dcy), z + (az - daz) + (cz2 - dcz),
          -cx2, -cy2, -cz2, -(ax - ax2), -(ay - ay2), -(az - az2), bx, by, bz);
  } else {
    gen3d(G, x, y, z, bx2, by2, bz2, cx2, cy2, cz2, ax2, ay2, az2);
    gen3d(G, x + bx2, y + by2, z + bz2, cx, cy, cz, ax2, ay2, az2, bx - bx2, by - by2, bz - bz2);
    gen3d(G, x + (bx2 - dbx) + (cx - dcx), y + (by2 - dby) + (cy - dcy), z + (bz2 - dbz) + (cz - dcz),
          ax, ay, az, -bx2, -by2, -bz2, -(cx - cx2), -(cy - cy2), -(cz - cz2));
    gen3d(G, x + (ax - dax) + bx2 + (cx - dcx), y + (ay - day) + by2 + (cy - dcy), z + (az - daz) + bz2 + (cz - dcz),
          -cx, -cy, -cz, -(ax - ax2), -(ay - ay2), -(az - az2), bx - bx2, by - by2, bz - bz2);
  }
}

// ============================ host: threefry ============================
static void tf2x32(uint32_t k0, uint32_t k1, uint32_t x0, uint32_t x1,
                   uint32_t& o0, uint32_t& o1) {
  uint32_t ks0 = k0, ks1 = k1, ks2 = k0 ^ k1 ^ 0x1BD11BDAu;
  const uint32_t ks[3] = {ks0, ks1, ks2};
  const int rot[2][4] = {{13, 15, 26, 6}, {17, 29, 16, 24}};
  x0 += ks[0]; x1 += ks[1];
  for (int i = 0; i < 5; i++) {
    for (int j = 0; j < 4; j++) {
      int rr = rot[i & 1][j];
      x0 += x1;
      x1 = (x1 << rr) | (x1 >> (32 - rr));
      x1 ^= x0;
    }
    x0 += ks[(i + 1) % 3];
    x1 += ks[(i + 2) % 3] + (uint32_t)(i + 1);
  }
  o0 = x0; o1 = x1;
}

static inline float bits_to_unit(uint32_t bits) {
  uint32_t fb = (bits >> 9) | 0x3f800000u;
  float f; memcpy(&f, &fb, 4);
  return f - 1.0f;
}

static void fill_idx(uint32_t K0, uint32_t K1, int* dst) {
  float u[NH * BLKSZ];
#if JAX_PARTITIONABLE
  for (int i = 0; i < NH * BLKSZ; i++) {
    uint32_t a, b; tf2x32(K0, K1, 0u, (uint32_t)i, a, b);
    u[i] = bits_to_unit(a ^ b);
  }
#else
  {
    const int n = NH * BLKSZ, hn = n / 2;
    for (int i = 0; i < hn; i++) {
      uint32_t a, b; tf2x32(K0, K1, (uint32_t)i, (uint32_t)(hn + i), a, b);
      u[i] = bits_to_unit(a);
      u[hn + i] = bits_to_unit(b);
    }
  }
#endif
  for (int h = 0; h < NH; h++) {
    const float* row = u + h * BLKSZ;
    bool used[BLKSZ] = {false};
    for (int r = 0; r < NKEEP; r++) {
      int best = -1; float bv = -2.0f;
      for (int g = 0; g < BLKSZ; g++)
        if (!used[g] && row[g] > bv) { bv = row[g]; best = g; }
      used[best] = true;
      dst[h * NKEEP + r] = best;
    }
  }
}

static void build_tables(int* tab) {
  static int yields[NVID];
  static int o2g_buf[NVID];
  static int g2o_buf[NVID];
  memset(o2g_buf, 0, sizeof(o2g_buf));
  memset(g2o_buf, 0, sizeof(g2o_buf));
  Gil G{yields, 0};
  gen3d(G, 0, 0, 0, kW, 0, 0, 0, kH, 0, 0, 0, kD);
  int n = G.n;
  if (n > NVID) n = NVID;
  for (int g = 0; g < n; g++) o2g_buf[g] = yields[g];
  for (int g = 0; g < n; g++) g2o_buf[yields[g]] = g;

  int* inmap = tab;
  int* outg  = tab + LSEQ;
  for (int g = 0; g < NVID; g++) inmap[g] = TEXT + o2g_buf[g];
  for (int t = 0; t < TEXT; t++) inmap[NVID + t] = t;
  for (int r = 0; r < TEXT; r++) outg[r] = NVID + r;
  for (int c = 0; c < NVID; c++) outg[TEXT + c] = g2o_buf[c];

  uint32_t kq0, kq1, kk0, kk1;
#if JAX_PARTITIONABLE
  tf2x32(0, 0, 0, 0, kq0, kq1);
  tf2x32(0, 0, 0, 1, kk0, kk1);
#else
  {
    uint32_t y00, y10, y01, y11;
    tf2x32(0, 0, 0, 2, y00, y10);
    tf2x32(0, 0, 1, 3, y01, y11);
    kq0 = y00; kq1 = y01; kk0 = y10; kk1 = y11;
  }
#endif
  fill_idx(kq0, kq1, tab + 2 * LSEQ);
  fill_idx(kk0, kk1, tab + 2 * LSEQ + NH * NKEEP);
}

}  // namespace

// ============================ device helpers ============================

typedef __attribute__((ext_vector_type(8))) short short8v;
typedef __attribute__((ext_vector_type(4))) float f32x4;

static __device__ inline unsigned short f2bf(float f) {
  unsigned u = __float_as_uint(f);
  unsigned r = u + 0x7FFFu + ((u >> 16) & 1u);  // RNE
  return (unsigned short)(r >> 16);
}
static __device__ inline float bf2f(unsigned short s) {
  return __uint_as_float(((unsigned)s) << 16);
}
static __device__ inline int cvtpk(float lo, float hi) {
  int r;
  asm("v_cvt_pk_bf16_f32 %0, %1, %2" : "=v"(r) : "v"(lo), "v"(hi));
  return r;
}

// ============================ device kernels ============================

__global__ __launch_bounds__(256) void k_rearr(
    const float* __restrict__ q, const float* __restrict__ k, const float* __restrict__ v,
    float* __restrict__ qr, float* __restrict__ kr,
    short* __restrict__ qrb, short* __restrict__ krb, short* __restrict__ vrb,
    const int* __restrict__ inmap) {
  long rid = (long)blockIdx.x * 4 + (threadIdx.x >> 6);
  int d = threadIdx.x & 63;
  const long total = 3L * NH * LPAD;
  if (rid >= total) return;
  int tsel = (int)(rid / ((long)NH * LPAD));
  long rem = rid - (long)tsel * NH * LPAD;
  int h = (int)(rem / LPAD);
  int i = (int)(rem % LPAD);
  const float* src = tsel == 0 ? q : (tsel == 1 ? k : v);
  float val = 0.f;
  if (i < LSEQ) val = src[((long)h * LSEQ + inmap[i]) * DD + d];
  long o = ((long)h * LPAD + i) * DD + d;
  if (tsel == 0) { qr[o] = val; qrb[o] = (short)f2bf(val); }
  else if (tsel == 1) { kr[o] = val; krb[o] = (short)f2bf(val); }
  else { vrb[o] = (short)f2bf(val); }
}

__global__ __launch_bounds__(256) void k_sample(
    const float* __restrict__ qr, const float* __restrict__ kr,
    float* __restrict__ sq, float* __restrict__ sk,
    const int* __restrict__ qidx, const int* __restrict__ kidx) {
  long rid = (long)blockIdx.x * 4 + (threadIdx.x >> 6);
  int d = threadIdx.x & 63;
  const long total = 2L * NH * NS;
  if (rid >= total) return;
  int tsel = (int)(rid / ((long)NH * NS));
  long rem = rid - (long)tsel * NH * NS;
  int h = (int)(rem / NS);
  int s = (int)(rem % NS);
  int b = s / NKEEP, t = s % NKEEP;
  const int* idx = tsel ? kidx : qidx;
  int p = b * BLKSZ + idx[h * NKEEP + t];
  if (p >= LSEQ) p = LSEQ - 1;
  const float* src = tsel ? kr : qr;
  float* dst = tsel ? sk : sq;
  dst[((long)h * NS + s) * DD + d] = src[((long)h * LPAD + p) * DD + d];
}

__global__ __launch_bounds__(256) void k_scores_pool(
    const float* __restrict__ sq, const float* __restrict__ sk, float* __restrict__ pool) {
  __shared__ float kt[NKEEP * DD];
  __shared__ float bins[NKEEP * NBLK];
  __shared__ float bpart[4][NKEEP];
  __shared__ float invden[NKEEP];
  int h = blockIdx.x / NBLK, qb = blockIdx.x % NBLK;
  int t = threadIdx.x;
  int r = t & 31;
  int c = t >> 5;
  float4 qv[16];
  {
    const float4* q4 = (const float4*)(sq + ((long)h * NS + qb * NKEEP + r) * DD);
#pragma unroll
    for (int i = 0; i < 16; i++) qv[i] = q4[i];
  }
  for (int i = t; i < NKEEP * NBLK; i += 256) bins[i] = 0.f;
  const float* skh = sk + (long)h * NS * DD;
  for (int kb = 0; kb < NBLK; kb++) {
    __syncthreads();
    const float4* src4 = (const float4*)(skh + (long)kb * NKEEP * DD);
    for (int i = t; i < NKEEP * DD / 4; i += 256) ((float4*)kt)[i] = src4[i];
    __syncthreads();
    float acc = 0.f;
#pragma unroll
    for (int i = 0; i < 4; i++) {
      int krow = c * 4 + i;
      const float4* k4 = (const float4*)(kt + krow * DD);
      float s = 0.f;
#pragma unroll
      for (int d4 = 0; d4 < 16; d4++) {
        float4 a = qv[d4], b = k4[d4];
        s += a.x * b.x + a.y * b.y + a.z * b.z + a.w * b.w;
      }
      acc += __expf(s * SCALE);
    }
    acc += __shfl_xor(acc, 32);
    if ((t & 32) == 0) bpart[t >> 6][r] = acc;
    __syncthreads();
    if (t < NKEEP) bins[t * NBLK + kb] = bpart[0][t] + bpart[1][t] + bpart[2][t] + bpart[3][t];
  }
  __syncthreads();
  if (t < NKEEP) {
    float s = 0.f;
    for (int kb = 0; kb < NBLK; kb++) s += bins[t * NBLK + kb];
    invden[t] = 1.0f / s;
  }
  __syncthreads();
  if (t < NBLK) {
    float s = 0.f;
    for (int r2 = 0; r2 < NKEEP; r2++) s += bins[r2 * NBLK + t] * invden[r2];
    pool[((long)h * NBLK + qb) * NBLK + t] = s;
  }
}

__global__ __launch_bounds__(192) void k_mask(
    const float* __restrict__ pool, int* __restrict__ mask) {
  __shared__ float row[NBLK];
  int h = blockIdx.x / NBLK, i = blockIdx.x % NBLK;
  int t = threadIdx.x;
  const float* pr = pool + ((long)h * NBLK + i) * NBLK;
  if (t < NBLK) row[t] = pr[t];
  __syncthreads();
  if (t < NBLK) {
    float pv = row[t];
    int rank = 0;
    for (int j = 0; j < NBLK; j++) {
      float o = row[j];
      rank += (o > pv) || (o == pv && j < t);
    }
    int val = 0;
    if (rank < 6) val = 1;
    else if (rank < 20) val = 2;
    else if (rank < 34) val = 4;
    else if (rank < 69) val = 8;
    if (t >= NBLK - 2) val = 1;
    if (i >= NBLK - 2) val = 1;
    mask[((long)h * NBLK + i) * NBLK + t] = val;
  }
}

__global__ __launch_bounds__(256) void k_poolkv(
    const short* __restrict__ krb, const short* __restrict__ vrb,
    short* __restrict__ Kpb, short* __restrict__ Vpb) {
  long rid = (long)blockIdx.x * 4 + (threadIdx.x >> 6);
  int d = threadIdx.x & 63;
  const long total = 2L * NH * NBLK * 112;
  if (rid >= total) return;
  int tsel = (int)(rid / ((long)NH * NBLK * 112));
  long rem = rid - (long)tsel * NH * NBLK * 112;
  int h = (int)(rem / (NBLK * 112));
  int rem2 = (int)(rem % (NBLK * 112));
  int j = rem2 / 112, p = rem2 % 112;
  int m, g;
  if (p < 64) { m = 2; g = p; }
  else if (p < 96) { m = 4; g = p - 64; }
  else { m = 8; g = p - 96; }
  const short* src = tsel ? vrb : krb;
  const short* base = src + ((long)h * LPAD + j * BLKSZ + g * m) * DD + d;
  float sum = 0.f;
  for (int r2 = 0; r2 < m; r2++) sum += bf2f((unsigned short)base[(long)r2 * DD]);
  short* dst = tsel ? Vpb : Kpb;
  dst[(((long)h * NBLK + j) * 112 + p) * DD + d] = (short)f2bf(sum / (float)m);
}

// ---------------- MFMA sparse attention ----------------
// grid = [heavy: NH*2*NSPLIT pieces (full-attn q-blocks, contiguous kv slices,
//         write unnormalized partials)] ++ [light: NH*137 masked blocks].
__global__ __launch_bounds__(256) void k_attn_mfma(
    const short* __restrict__ qrb, const short* __restrict__ krb,
    const short* __restrict__ vrb,
    const short* __restrict__ Kpb, const short* __restrict__ Vpb,
    const int* __restrict__ mask,
    float* __restrict__ outr, float* __restrict__ part, float* __restrict__ plsum) {
  __shared__ int glist[MAXG];
  __shared__ int ngarr[NBLK + 1];
  __shared__ __align__(16) short Kt[64 * 64];   // swizzled row-major
  __shared__ __align__(16) short Vt[64 * 68];   // V^T [d][kv], stride 68
  __shared__ int smeta;

  int bid = blockIdx.x;
  int tid = threadIdx.x;
  bool heavy = bid < NHEAVYB;
  int h, qi, c0, c1, slot = 0;
  if (heavy) {
    int split = bid % NSPLIT;
    int hq = bid / NSPLIT;          // 0..15
    h = hq >> 1;
    qi = NBLK - 2 + (hq & 1);
    c0 = split * CHPER;
    c1 = c0 + CHPER; if (c1 > HCHUNK) c1 = HCHUNK;
    slot = hq * NSPLIT + split;
  } else {
    int lb = bid - NHEAVYB;
    h = lb / (NBLK - 2);
    qi = lb % (NBLK - 2);
    c0 = 0; c1 = 0;
  }

  // ---- light: group list ----
  int myng = 0, mylvl = 0, myG = 0;
  if (!heavy && tid < NBLK) {
    int mv = mask[((long)h * NBLK + qi) * NBLK + tid];
    if (mv) {
      mylvl = (mv == 1) ? 0 : (mv == 2) ? 1 : (mv == 4) ? 2 : 3;
      myG = ((tid == NBLK - 1) ? VLAST : BLKSZ) >> mylvl;
      myng = (myG + 15) >> 4;
    }
    ngarr[tid] = myng;
  }
  __syncthreads();
  if (!heavy && tid == 0) {
    int run = 0;
    for (int j = 0; j < NBLK; j++) { int t2 = ngarr[j]; ngarr[j] = run; run += t2; }
    int tot = run;
    while (tot & 3) glist[tot++] = 0;
    smeta = tot >> 2;
  }
  __syncthreads();
  if (!heavy && tid < NBLK && myng) {
    int off = ngarr[tid];
    int src0, pooled;
    if (mylvl == 0) { src0 = h * LPAD + tid * BLKSZ; pooled = 0; }
    else {
      int loff = (mylvl == 1) ? 0 : (mylvl == 2) ? 64 : 96;
      src0 = (h * NBLK + tid) * 112 + loff; pooled = 1;
    }
    for (int g = 0; g < myng; g++) {
      int cnt = myG - 16 * g; if (cnt > 16) cnt = 16;
      glist[off + g] = (src0 + 16 * g) | (cnt << 24) | (mylvl << 29) | (pooled << 31);
    }
  }
  __syncthreads();
  if (!heavy) c1 = smeta;

  int lane = tid & 63, wid = tid >> 6;
  int lm = lane & 15, lg = lane >> 4;

  // ---- Q fragments ----
  short8v Qf[2][2];
#pragma unroll
  for (int mt = 0; mt < 2; mt++)
#pragma unroll
    for (int ks = 0; ks < 2; ks++) {
      long row = (long)h * LPAD + qi * BLKSZ + wid * 32 + mt * 16 + lm;
      Qf[mt][ks] = *(const short8v*)(qrb + row * DD + ks * 32 + lg * 8);
    }

  f32x4 Oacc[4][2];
#pragma unroll
  for (int a = 0; a < 4; a++)
#pragma unroll
    for (int b = 0; b < 2; b++) { f32x4 z = {0.f, 0.f, 0.f, 0.f}; Oacc[a][b] = z; }
  float lrow0 = 0.f, lrow1 = 0.f;

  // staging map: row sr = tid&63, dims sd0 = (tid>>6)*16 (+8)
  int sr = tid & 63;
  int sd0 = (tid >> 6) * 16;

  short8v pkA, pkB, pvA, pvB;
  auto loadc = [&](int c) {
    long srcrow;
    const short *kbp, *vbp;
    if (heavy) {
      srcrow = (long)h * LPAD + (long)c * 64 + sr;
      kbp = krb; vbp = vrb;
    } else {
      unsigned e = (unsigned)glist[4 * c + (sr >> 4)];
      srcrow = (long)((e & 0xFFFFFFu) + (sr & 15));
      kbp = (e >> 31) ? Kpb : krb;
      vbp = (e >> 31) ? Vpb : vrb;
    }
    const short8v* kp = (const short8v*)(kbp + srcrow * DD + sd0);
    const short8v* vp = (const short8v*)(vbp + srcrow * DD + sd0);
    pkA = kp[0]; pkB = kp[1];
    pvA = vp[0]; pvB = vp[1];
  };

  loadc(c0);

  for (int c = c0; c < c1; c++) {
    __syncthreads();
    {  // stage from regs
      int sw = (sr & 7) << 3;
      *(short8v*)&Kt[sr * 64 + (sd0 ^ sw)] = pkA;
      *(short8v*)&Kt[sr * 64 + ((sd0 + 8) ^ sw)] = pkB;
#pragma unroll
      for (int i = 0; i < 8; i++) {
        Vt[(sd0 + i) * 68 + sr] = pvA[i];
        Vt[(sd0 + 8 + i) * 68 + sr] = pvB[i];
      }
    }
    __syncthreads();
    if (c + 1 < c1) loadc(c + 1);

    // metadata
    int cntv[4]; float biasv[4];
    if (heavy) {
#pragma unroll
      for (int g = 0; g < 4; g++) {
        int cc = LSEQ - 16 * (4 * c + g);
        cntv[g] = cc <= 0 ? 0 : (cc >= 16 ? 16 : cc);
        biasv[g] = 0.f;
      }
    } else {
#pragma unroll
      for (int g = 0; g < 4; g++) {
        unsigned e = (unsigned)glist[4 * c + g];
        cntv[g] = (e >> 24) & 31;
        biasv[g] = (float)((e >> 29) & 3) * LN2F;
      }
    }
    bool allfull = (cntv[0] == 16) & (cntv[1] == 16) & (cntv[2] == 16) & (cntv[3] == 16);

    // K frags
    short8v Kf[4][2];
#pragma unroll
    for (int nt = 0; nt < 4; nt++)
#pragma unroll
      for (int ks = 0; ks < 2; ks++)
        Kf[nt][ks] = *(short8v*)&Kt[(nt * 16 + lm) * 64 + ((ks * 32 + lg * 8) ^ ((lm & 7) << 3))];

    // QK^T + softmax + pack, per mt
    short8v Pf[2][2];
#pragma unroll
    for (int mt = 0; mt < 2; mt++) {
      f32x4 aq[4];
#pragma unroll
      for (int nt = 0; nt < 4; nt++) {
        f32x4 z = {0.f, 0.f, 0.f, 0.f};
        f32x4 a = __builtin_amdgcn_mfma_f32_16x16x32_bf16(Kf[nt][0], Qf[mt][0], z, 0, 0, 0);
        aq[nt] = __builtin_amdgcn_mfma_f32_16x16x32_bf16(Kf[nt][1], Qf[mt][1], a, 0, 0, 0);
      }
      float ps[16];
      if (allfull) {
#pragma unroll
        for (int nt = 0; nt < 4; nt++)
#pragma unroll
          for (int i = 0; i < 4; i++)
            ps[nt * 4 + i] = __expf(fmaf(aq[nt][i], SCALE, biasv[nt]));
      } else {
#pragma unroll
        for (int nt = 0; nt < 4; nt++)
#pragma unroll
          for (int i = 0; i < 4; i++) {
            int kvr = lg * 4 + i;
            ps[nt * 4 + i] = (kvr < cntv[nt]) ? __expf(fmaf(aq[nt][i], SCALE, biasv[nt])) : 0.f;
          }
      }
      float lsum = 0.f;
#pragma unroll
      for (int i = 0; i < 16; i++) lsum += ps[i];
      if (mt == 0) lrow0 += lsum; else lrow1 += lsum;
#pragma unroll
      for (int H = 0; H < 2; H++) {
        union { int i[4]; short8v v; } u;
        u.i[0] = cvtpk(ps[8 * H + 0], ps[8 * H + 1]);
        u.i[1] = cvtpk(ps[8 * H + 2], ps[8 * H + 3]);
        u.i[2] = cvtpk(ps[8 * H + 4], ps[8 * H + 5]);
        u.i[3] = cvtpk(ps[8 * H + 6], ps[8 * H + 7]);
        Pf[mt][H] = u.v;
      }
    }

    // PV
#pragma unroll
    for (int mtp = 0; mtp < 4; mtp++) {
      int d68 = (mtp * 16 + lm) * 68;
#pragma unroll
      for (int H = 0; H < 2; H++) {
        short4 lo = *(short4*)&Vt[d68 + H * 32 + lg * 4];
        short4 hi = *(short4*)&Vt[d68 + H * 32 + 16 + lg * 4];
        short8v vf;
        vf[0] = lo.x; vf[1] = lo.y; vf[2] = lo.z; vf[3] = lo.w;
        vf[4] = hi.x; vf[5] = hi.y; vf[6] = hi.z; vf[7] = hi.w;
        Oacc[mtp][0] = __builtin_amdgcn_mfma_f32_16x16x32_bf16(vf, Pf[0][H], Oacc[mtp][0], 0, 0, 0);
        Oacc[mtp][1] = __builtin_amdgcn_mfma_f32_16x16x32_bf16(vf, Pf[1][H], Oacc[mtp][1], 0, 0, 0);
      }
    }
  }

  // ---- reduce row sums across the 4 lane-groups ----
  lrow0 += __shfl_xor(lrow0, 16); lrow0 += __shfl_xor(lrow0, 32);
  lrow1 += __shfl_xor(lrow1, 16); lrow1 += __shfl_xor(lrow1, 32);

  if (heavy) {
    // unnormalized partials + lsum
    if (lg == 0) {
      plsum[(long)slot * BLKSZ + wid * 32 + lm] = lrow0;
      plsum[(long)slot * BLKSZ + wid * 32 + 16 + lm] = lrow1;
    }
#pragma unroll
    for (int mt = 0; mt < 2; mt++) {
      int lrow = wid * 32 + mt * 16 + lm;
      float* orow = part + ((long)slot * BLKSZ + lrow) * DD;
#pragma unroll
      for (int mtp = 0; mtp < 4; mtp++) {
        f32x4 o = Oacc[mtp][mt];
        *(float4*)(orow + mtp * 16 + lg * 4) = make_float4(o[0], o[1], o[2], o[3]);
      }
    }
  } else {
    float inv0 = 1.0f / lrow0, inv1 = 1.0f / lrow1;
#pragma unroll
    for (int mt = 0; mt < 2; mt++) {
      int grow = qi * BLKSZ + wid * 32 + mt * 16 + lm;
      float inv = mt ? inv1 : inv0;
      float* orow = outr + ((long)h * LSEQ + grow) * DD;
#pragma unroll
      for (int mtp = 0; mtp < 4; mtp++) {
        f32x4 o = Oacc[mtp][mt];
        *(float4*)(orow + mtp * 16 + lg * 4) =
            make_float4(o[0] * inv, o[1] * inv, o[2] * inv, o[3] * inv);
      }
    }
  }
}

// combine heavy partials -> outr
__global__ __launch_bounds__(256) void k_combine(
    const float* __restrict__ part, const float* __restrict__ plsum,
    float* __restrict__ outr) {
  int hq = blockIdx.x;             // 0..15
  int h = hq >> 1;
  int qi = NBLK - 2 + (hq & 1);
  int t = threadIdx.x;
  int row = t >> 1;
  int dbase = (t & 1) * 32;
  float l = 0.f;
  for (int s = 0; s < NSPLIT; s++) l += plsum[(long)(hq * NSPLIT + s) * BLKSZ + row];
  int grow = qi * BLKSZ + row;
  if (grow >= LSEQ) return;
  float inv = 1.0f / l;
  float* orow = outr + ((long)h * LSEQ + grow) * DD;
  for (int d = dbase; d < dbase + 32; d += 4) {
    float4 acc = make_float4(0.f, 0.f, 0.f, 0.f);
    for (int s = 0; s < NSPLIT; s++) {
      float4 p4 = *(const float4*)&part[((long)(hq * NSPLIT + s) * BLKSZ + row) * DD + d];
      acc.x += p4.x; acc.y += p4.y; acc.z += p4.z; acc.w += p4.w;
    }
    *(float4*)(orow + d) = make_float4(acc.x * inv, acc.y * inv, acc.z * inv, acc.w * inv);
  }
}

// final gather
__global__ __launch_bounds__(256) void k_out(
    const float* __restrict__ outr, const int* __restrict__ outg,
    float* __restrict__ out) {
  long rid = (long)blockIdx.x * 4 + (threadIdx.x >> 6);
  int d = threadIdx.x & 63;
  const long total = (long)NH * LSEQ;
  if (rid >= total) return;
  int h = (int)(rid / LSEQ);
  int r = (int)(rid % LSEQ);
  int src = outg[r];
  out[((long)h * LSEQ + r) * DD + d] = outr[((long)h * LSEQ + src) * DD + d];
}

// ============================ launch ============================

extern "C" void kernel_launch(void* const* d_in, const int* in_sizes, int n_in,
                              void* d_out, int out_size, void* d_ws, size_t ws_size,
                              hipStream_t stream) {
  (void)in_sizes; (void)n_in; (void)out_size; (void)ws_size;
  const float* q = (const float*)d_in[0];
  const float* k = (const float*)d_in[1];
  const float* v = (const float*)d_in[2];
  float* ws = (float*)d_ws;
  float* out = (float*)d_out;

  static int* htab = nullptr;
  if (!htab) { (void)hipHostMalloc((void**)&htab, TAB_INTS * sizeof(int)); }
  build_tables(htab);

  int* dtab = (int*)(ws + F_TB);
  int* inmap = dtab;
  int* outg = dtab + LSEQ;
  int* qidx = dtab + 2 * LSEQ;
  int* kidx = qidx + NH * NKEEP;
  int* dmask = (int*)(ws + F_MK);
  float* qr = ws + F_QR; float* kr = ws + F_KR;
  short* qrb = (short*)(ws + F_QB);
  short* krb = (short*)(ws + F_KB);
  short* vrb = (short*)(ws + F_VB);
  float* sq = ws + F_SQ; float* sk = ws + F_SK; float* pool = ws + F_PL;
  short* Kpb = (short*)(ws + F_KPB);
  short* Vpb = (short*)(ws + F_VPB);
  float* outr = ws + F_OR;
  float* part = ws + F_PT;
  float* plsum = ws + F_PS;

  hipMemcpyAsync(dtab, htab, TAB_INTS * sizeof(int), hipMemcpyHostToDevice, stream);

  {
    long rows = 3L * NH * LPAD;
    k_rearr<<<dim3((unsigned)((rows + 3) / 4)), 256, 0, stream>>>(
        q, k, v, qr, kr, qrb, krb, vrb, inmap);
  }
  {
    long rows = 2L * NH * NS;
    k_sample<<<dim3((unsigned)((rows + 3) / 4)), 256, 0, stream>>>(qr, kr, sq, sk, qidx, kidx);
  }
  k_scores_pool<<<dim3(NH * NBLK), 256, 0, stream>>>(sq, sk, pool);
  k_mask<<<dim3(NH * NBLK), 192, 0, stream>>>(pool, dmask);
  {
    long rows = 2L * NH * NBLK * 112;
    k_poolkv<<<dim3((unsigned)((rows + 3) / 4)), 256, 0, stream>>>(krb, vrb, Kpb, Vpb);
  }
  k_attn_mfma<<<dim3(NHEAVYB + NLIGHT), 256, 0, stream>>>(
      qrb, krb, vrb, Kpb, Vpb, dmask, outr, part, plsum);
  k_combine<<<dim3(NH * 2), 256, 0, stream>>>(part, plsum, outr);
  {
    long rows = (long)NH * LSEQ;
    k_out<<<dim3((unsigned)((rows + 3) / 4)), 256, 0, stream>>>(outr, outg, out);
  }
}

// Round 7
// 810.157 us; speedup vs baseline: 14.6744x; 1.3334x over previous
//
#include <hip/hip_runtime.h>
#include <stdint.h>
#include <string.h>
#include <stdlib.h>

#define JAX_PARTITIONABLE 1

namespace {

constexpr int kW = 45, kH = 30, kD = 13;
constexpr int NVID = kW * kH * kD;          // 17550
constexpr int TEXT = 226;
constexpr int LSEQ = TEXT + NVID;           // 17776
constexpr int BLKSZ = 128;
constexpr int NBLK = 139;
constexpr int LPAD = NBLK * BLKSZ;          // 17792
constexpr int NKEEP = 32;
constexpr int NS = NBLK * NKEEP;            // 4448
constexpr int NH = 8;
constexpr int DD = 64;
constexpr int VLAST = LSEQ - (NBLK - 1) * BLKSZ;  // 112
constexpr float SCALE = 0.125f;
constexpr float LN2F = 0.69314718055994530942f;
constexpr int MAXG = 188;                   // light rows: <=182 groups (+pad)

// heavy split
constexpr int NSPLIT = 16;
constexpr int HCHUNK = (LSEQ + 63) / 64;    // 278 chunks of 64 kv
constexpr int CHPER = (HCHUNK + NSPLIT - 1) / NSPLIT;  // 18
constexpr int NHEAVYB = NH * 2 * NSPLIT;    // 256 blocks
constexpr int NLIGHT = NH * (NBLK - 2);     // 1096

// ---------------- workspace layout (float units) ----------------
constexpr long SZ_R  = (long)NH * LPAD * DD;        // fp32
constexpr long SZ_RB = SZ_R / 2;                    // bf16, float units
constexpr long SZ_S  = (long)NH * NS * DD;
constexpr long SZ_PL = (long)NH * NBLK * NBLK;
constexpr long SZ_KPB = (long)NH * NBLK * 112 * DD / 2;
constexpr long SZ_O  = (long)NH * LSEQ * DD;
constexpr long SZ_PT = (long)NH * 2 * NSPLIT * BLKSZ * DD;  // heavy partials
constexpr long SZ_PS = (long)NH * 2 * NSPLIT * BLKSZ;       // heavy lsums
constexpr long F_QR = 0;
constexpr long F_KR = F_QR + SZ_R;
constexpr long F_QB = F_KR + SZ_R;
constexpr long F_KB = F_QB + SZ_RB;
constexpr long F_VB = F_KB + SZ_RB;
constexpr long F_SQ = F_VB + SZ_RB;
constexpr long F_SK = F_SQ + SZ_S;
constexpr long F_PL = F_SK + SZ_S;
constexpr long F_KPB = F_PL + SZ_PL;
constexpr long F_VPB = F_KPB + SZ_KPB;
constexpr long F_MK = F_VPB + SZ_KPB;               // int32
constexpr long F_OR = F_MK + SZ_PL;
constexpr long F_PT = F_OR + SZ_O;
constexpr long F_PS = F_PT + SZ_PT;
constexpr long F_TB = F_PS + SZ_PS;                 // int32 tables
constexpr int TAB_INTS = 2 * LSEQ + 2 * NH * NKEEP;

// ============================ host: gilbert =============================
// Faithful port of the PROBLEM's _gen3d (volume-deficient regular-else branch
// included). o2g keeps trailing zeros; g2o keeps zeros for missed cells.
struct Gil { int* out; int n; };
static inline int sgn_i(int v) { return (v > 0) - (v < 0); }
static inline int fd2(int a) { return a >= 0 ? a / 2 : -((-a + 1) / 2); }

static void gen3d(Gil& G, int x, int y, int z,
                  int ax, int ay, int az,
                  int bx, int by, int bz,
                  int cx, int cy, int cz) {
  int w = abs(ax + ay + az), h = abs(bx + by + bz), d = abs(cx + cy + cz);
  int dax = sgn_i(ax), day = sgn_i(ay), daz = sgn_i(az);
  int dbx = sgn_i(bx), dby = sgn_i(by), dbz = sgn_i(bz);
  int dcx = sgn_i(cx), dcy = sgn_i(cy), dcz = sgn_i(cz);
  if (h == 1 && d == 1) { for (int i = 0; i < w; i++) { G.out[G.n++] = x + kW * (y + kH * z); x += dax; y += day; z += daz; } return; }
  if (w == 1 && d == 1) { for (int i = 0; i < h; i++) { G.out[G.n++] = x + kW * (y + kH * z); x += dbx; y += dby; z += dbz; } return; }
  if (w == 1 && h == 1) { for (int i = 0; i < d; i++) { G.out[G.n++] = x + kW * (y + kH * z); x += dcx; y += dcy; z += dcz; } return; }
  int ax2 = fd2(ax), ay2 = fd2(ay), az2 = fd2(az);
  int bx2 = fd2(bx), by2 = fd2(by), bz2 = fd2(bz);
  int cx2 = fd2(cx), cy2 = fd2(cy), cz2 = fd2(cz);
  int w2 = abs(ax2 + ay2 + az2), h2 = abs(bx2 + by2 + bz2), d2 = abs(cx2 + cy2 + cz2);
  if ((w2 & 1) && w > 2) { ax2 += dax; ay2 += day; az2 += daz; }
  if ((h2 & 1) && h > 2) { bx2 += dbx; by2 += dby; bz2 += dbz; }
  if ((d2 & 1) && d > 2) { cx2 += dcx; cy2 += dcy; cz2 += dcz; }
  if (2 * w > 3 * h && 2 * w > 3 * d) {
    gen3d(G, x, y, z, ax2, ay2, az2, bx, by, bz, cx, cy, cz);
    gen3d(G, x + ax2, y + ay2, z + az2, ax - ax2, ay - ay2, az - az2, bx, by, bz, cx, cy, cz);
  } else if (3 * h > 4 * d) {
    gen3d(G, x, y, z, bx2, by2, bz2, cx, cy, cz, ax2, ay2, az2);
    gen3d(G, x + bx2, y + by2, z + bz2, ax, ay, az, bx - bx2, by - by2, bz - bz2, cx, cy, cz);
    gen3d(G, x + (ax - dax) + (bx2 - dbx), y + (ay - day) + (by2 - dby), z + (az - daz) + (bz2 - dbz),
          -bx2, -by2, -bz2, cx, cy, cz, -(ax - ax2), -(ay - ay2), -(az - az2));
  } else if (3 * d > 4 * h) {
    gen3d(G, x, y, z, cx2, cy2, cz2, ax2, ay2, az2, bx, by, bz);
    gen3d(G, x + cx2, y + cy2, z + cz2, ax, ay, az, bx, by, bz, cx - cx2, cy - cy2, cz - cz2);
    gen3d(G, x + (ax - dax) + (cx2 - dcx), y + (ay - day) + (cy2 - dcy), z + (az - daz) + (cz2 - dcz),
          -cx2, -cy2, -cz2, -(ax - ax2), -(ay - ay2), -(az - az2), bx, by, bz);
  } else {
    gen3d(G, x, y, z, bx2, by2, bz2, cx2, cy2, cz2, ax2, ay2, az2);
    gen3d(G, x + bx2, y + by2, z + bz2, cx, cy, cz, ax2, ay2, az2, bx - bx2, by - by2, bz - bz2);
    gen3d(G, x + (bx2 - dbx) + (cx - dcx), y + (by2 - dby) + (cy - dcy), z + (bz2 - dbz) + (cz - dcz),
          ax, ay, az, -bx2, -by2, -bz2, -(cx - cx2), -(cy - cy2), -(cz - cz2));
    gen3d(G, x + (ax - dax) + bx2 + (cx - dcx), y + (ay - day) + by2 + (cy - dcy), z + (az - daz) + bz2 + (cz - dcz),
          -cx, -cy, -cz, -(ax - ax2), -(ay - ay2), -(az - az2), bx - bx2, by - by2, bz - bz2);
  }
}

// ============================ host: threefry ============================
static void tf2x32(uint32_t k0, uint32_t k1, uint32_t x0, uint32_t x1,
                   uint32_t& o0, uint32_t& o1) {
  uint32_t ks0 = k0, ks1 = k1, ks2 = k0 ^ k1 ^ 0x1BD11BDAu;
  const uint32_t ks[3] = {ks0, ks1, ks2};
  const int rot[2][4] = {{13, 15, 26, 6}, {17, 29, 16, 24}};
  x0 += ks[0]; x1 += ks[1];
  for (int i = 0; i < 5; i++) {
    for (int j = 0; j < 4; j++) {
      int rr = rot[i & 1][j];
      x0 += x1;
      x1 = (x1 << rr) | (x1 >> (32 - rr));
      x1 ^= x0;
    }
    x0 += ks[(i + 1) % 3];
    x1 += ks[(i + 2) % 3] + (uint32_t)(i + 1);
  }
  o0 = x0; o1 = x1;
}

static inline float bits_to_unit(uint32_t bits) {
  uint32_t fb = (bits >> 9) | 0x3f800000u;
  float f; memcpy(&f, &fb, 4);
  return f - 1.0f;
}

static void fill_idx(uint32_t K0, uint32_t K1, int* dst) {
  float u[NH * BLKSZ];
#if JAX_PARTITIONABLE
  for (int i = 0; i < NH * BLKSZ; i++) {
    uint32_t a, b; tf2x32(K0, K1, 0u, (uint32_t)i, a, b);
    u[i] = bits_to_unit(a ^ b);
  }
#else
  {
    const int n = NH * BLKSZ, hn = n / 2;
    for (int i = 0; i < hn; i++) {
      uint32_t a, b; tf2x32(K0, K1, (uint32_t)i, (uint32_t)(hn + i), a, b);
      u[i] = bits_to_unit(a);
      u[hn + i] = bits_to_unit(b);
    }
  }
#endif
  for (int h = 0; h < NH; h++) {
    const float* row = u + h * BLKSZ;
    bool used[BLKSZ] = {false};
    for (int r = 0; r < NKEEP; r++) {
      int best = -1; float bv = -2.0f;
      for (int g = 0; g < BLKSZ; g++)
        if (!used[g] && row[g] > bv) { bv = row[g]; best = g; }
      used[best] = true;
      dst[h * NKEEP + r] = best;
    }
  }
}

static void build_tables(int* tab) {
  static int yields[NVID];
  static int o2g_buf[NVID];
  static int g2o_buf[NVID];
  memset(o2g_buf, 0, sizeof(o2g_buf));
  memset(g2o_buf, 0, sizeof(g2o_buf));
  Gil G{yields, 0};
  gen3d(G, 0, 0, 0, kW, 0, 0, 0, kH, 0, 0, 0, kD);
  int n = G.n;
  if (n > NVID) n = NVID;
  for (int g = 0; g < n; g++) o2g_buf[g] = yields[g];
  for (int g = 0; g < n; g++) g2o_buf[yields[g]] = g;

  int* inmap = tab;
  int* outg  = tab + LSEQ;
  for (int g = 0; g < NVID; g++) inmap[g] = TEXT + o2g_buf[g];
  for (int t = 0; t < TEXT; t++) inmap[NVID + t] = t;
  for (int r = 0; r < TEXT; r++) outg[r] = NVID + r;
  for (int c = 0; c < NVID; c++) outg[TEXT + c] = g2o_buf[c];

  uint32_t kq0, kq1, kk0, kk1;
#if JAX_PARTITIONABLE
  tf2x32(0, 0, 0, 0, kq0, kq1);
  tf2x32(0, 0, 0, 1, kk0, kk1);
#else
  {
    uint32_t y00, y10, y01, y11;
    tf2x32(0, 0, 0, 2, y00, y10);
    tf2x32(0, 0, 1, 3, y01, y11);
    kq0 = y00; kq1 = y01; kk0 = y10; kk1 = y11;
  }
#endif
  fill_idx(kq0, kq1, tab + 2 * LSEQ);
  fill_idx(kk0, kk1, tab + 2 * LSEQ + NH * NKEEP);
}

}  // namespace

// ============================ device helpers ============================

typedef __attribute__((ext_vector_type(8))) short short8v;
typedef __attribute__((ext_vector_type(4))) float f32x4;

static __device__ inline unsigned short f2bf(float f) {
  unsigned u = __float_as_uint(f);
  unsigned r = u + 0x7FFFu + ((u >> 16) & 1u);  // RNE
  return (unsigned short)(r >> 16);
}
static __device__ inline float bf2f(unsigned short s) {
  return __uint_as_float(((unsigned)s) << 16);
}
static __device__ inline int cvtpk(float lo, float hi) {
  int r;
  asm("v_cvt_pk_bf16_f32 %0, %1, %2" : "=v"(r) : "v"(lo), "v"(hi));
  return r;
}

// ============================ device kernels ============================

__global__ __launch_bounds__(256) void k_rearr(
    const float* __restrict__ q, const float* __restrict__ k, const float* __restrict__ v,
    float* __restrict__ qr, float* __restrict__ kr,
    short* __restrict__ qrb, short* __restrict__ krb, short* __restrict__ vrb,
    const int* __restrict__ inmap) {
  long rid = (long)blockIdx.x * 4 + (threadIdx.x >> 6);
  int d = threadIdx.x & 63;
  const long total = 3L * NH * LPAD;
  if (rid >= total) return;
  int tsel = (int)(rid / ((long)NH * LPAD));
  long rem = rid - (long)tsel * NH * LPAD;
  int h = (int)(rem / LPAD);
  int i = (int)(rem % LPAD);
  const float* src = tsel == 0 ? q : (tsel == 1 ? k : v);
  float val = 0.f;
  if (i < LSEQ) val = src[((long)h * LSEQ + inmap[i]) * DD + d];
  long o = ((long)h * LPAD + i) * DD + d;
  if (tsel == 0) { qr[o] = val; qrb[o] = (short)f2bf(val); }
  else if (tsel == 1) { kr[o] = val; krb[o] = (short)f2bf(val); }
  else { vrb[o] = (short)f2bf(val); }
}

__global__ __launch_bounds__(256) void k_sample(
    const float* __restrict__ qr, const float* __restrict__ kr,
    float* __restrict__ sq, float* __restrict__ sk,
    const int* __restrict__ qidx, const int* __restrict__ kidx) {
  long rid = (long)blockIdx.x * 4 + (threadIdx.x >> 6);
  int d = threadIdx.x & 63;
  const long total = 2L * NH * NS;
  if (rid >= total) return;
  int tsel = (int)(rid / ((long)NH * NS));
  long rem = rid - (long)tsel * NH * NS;
  int h = (int)(rem / NS);
  int s = (int)(rem % NS);
  int b = s / NKEEP, t = s % NKEEP;
  const int* idx = tsel ? kidx : qidx;
  int p = b * BLKSZ + idx[h * NKEEP + t];
  if (p >= LSEQ) p = LSEQ - 1;
  const float* src = tsel ? kr : qr;
  float* dst = tsel ? sk : sq;
  dst[((long)h * NS + s) * DD + d] = src[((long)h * LPAD + p) * DD + d];
}

__global__ __launch_bounds__(256) void k_scores_pool(
    const float* __restrict__ sq, const float* __restrict__ sk, float* __restrict__ pool) {
  __shared__ float kt[NKEEP * DD];
  __shared__ float bins[NKEEP * NBLK];
  __shared__ float bpart[4][NKEEP];
  __shared__ float invden[NKEEP];
  int h = blockIdx.x / NBLK, qb = blockIdx.x % NBLK;
  int t = threadIdx.x;
  int r = t & 31;
  int c = t >> 5;
  float4 qv[16];
  {
    const float4* q4 = (const float4*)(sq + ((long)h * NS + qb * NKEEP + r) * DD);
#pragma unroll
    for (int i = 0; i < 16; i++) qv[i] = q4[i];
  }
  for (int i = t; i < NKEEP * NBLK; i += 256) bins[i] = 0.f;
  const float* skh = sk + (long)h * NS * DD;
  for (int kb = 0; kb < NBLK; kb++) {
    __syncthreads();
    const float4* src4 = (const float4*)(skh + (long)kb * NKEEP * DD);
    for (int i = t; i < NKEEP * DD / 4; i += 256) ((float4*)kt)[i] = src4[i];
    __syncthreads();
    float acc = 0.f;
#pragma unroll
    for (int i = 0; i < 4; i++) {
      int krow = c * 4 + i;
      const float4* k4 = (const float4*)(kt + krow * DD);
      float s = 0.f;
#pragma unroll
      for (int d4 = 0; d4 < 16; d4++) {
        float4 a = qv[d4], b = k4[d4];
        s += a.x * b.x + a.y * b.y + a.z * b.z + a.w * b.w;
      }
      acc += __expf(s * SCALE);
    }
    acc += __shfl_xor(acc, 32);
    if ((t & 32) == 0) bpart[t >> 6][r] = acc;
    __syncthreads();
    if (t < NKEEP) bins[t * NBLK + kb] = bpart[0][t] + bpart[1][t] + bpart[2][t] + bpart[3][t];
  }
  __syncthreads();
  if (t < NKEEP) {
    float s = 0.f;
    for (int kb = 0; kb < NBLK; kb++) s += bins[t * NBLK + kb];
    invden[t] = 1.0f / s;
  }
  __syncthreads();
  if (t < NBLK) {
    float s = 0.f;
    for (int r2 = 0; r2 < NKEEP; r2++) s += bins[r2 * NBLK + t] * invden[r2];
    pool[((long)h * NBLK + qb) * NBLK + t] = s;
  }
}

__global__ __launch_bounds__(192) void k_mask(
    const float* __restrict__ pool, int* __restrict__ mask) {
  __shared__ float row[NBLK];
  int h = blockIdx.x / NBLK, i = blockIdx.x % NBLK;
  int t = threadIdx.x;
  const float* pr = pool + ((long)h * NBLK + i) * NBLK;
  if (t < NBLK) row[t] = pr[t];
  __syncthreads();
  if (t < NBLK) {
    float pv = row[t];
    int rank = 0;
    for (int j = 0; j < NBLK; j++) {
      float o = row[j];
      rank += (o > pv) || (o == pv && j < t);
    }
    int val = 0;
    if (rank < 6) val = 1;
    else if (rank < 20) val = 2;
    else if (rank < 34) val = 4;
    else if (rank < 69) val = 8;
    if (t >= NBLK - 2) val = 1;
    if (i >= NBLK - 2) val = 1;
    mask[((long)h * NBLK + i) * NBLK + t] = val;
  }
}

__global__ __launch_bounds__(256) void k_poolkv(
    const short* __restrict__ krb, const short* __restrict__ vrb,
    short* __restrict__ Kpb, short* __restrict__ Vpb) {
  long rid = (long)blockIdx.x * 4 + (threadIdx.x >> 6);
  int d = threadIdx.x & 63;
  const long total = 2L * NH * NBLK * 112;
  if (rid >= total) return;
  int tsel = (int)(rid / ((long)NH * NBLK * 112));
  long rem = rid - (long)tsel * NH * NBLK * 112;
  int h = (int)(rem / (NBLK * 112));
  int rem2 = (int)(rem % (NBLK * 112));
  int j = rem2 / 112, p = rem2 % 112;
  int m, g;
  if (p < 64) { m = 2; g = p; }
  else if (p < 96) { m = 4; g = p - 64; }
  else { m = 8; g = p - 96; }
  const short* src = tsel ? vrb : krb;
  const short* base = src + ((long)h * LPAD + j * BLKSZ + g * m) * DD + d;
  float sum = 0.f;
  for (int r2 = 0; r2 < m; r2++) sum += bf2f((unsigned short)base[(long)r2 * DD]);
  short* dst = tsel ? Vpb : Kpb;
  dst[(((long)h * NBLK + j) * 112 + p) * DD + d] = (short)f2bf(sum / (float)m);
}

// ---------------- MFMA sparse attention: LIGHT (masked) blocks ----------------
__global__ __launch_bounds__(256, 1) void k_attn_light(
    const short* __restrict__ qrb, const short* __restrict__ krb,
    const short* __restrict__ vrb,
    const short* __restrict__ Kpb, const short* __restrict__ Vpb,
    const int* __restrict__ mask,
    float* __restrict__ outr) {
  __shared__ int glist[MAXG];
  __shared__ int ngarr[NBLK + 1];
  __shared__ __align__(16) short Kt[64 * 64];   // swizzled row-major
  __shared__ __align__(16) short Vt[64 * 68];   // V^T [d][kv], stride 68
  __shared__ int smeta;

  int bid = blockIdx.x;
  int h = bid / (NBLK - 2);
  int qi = bid % (NBLK - 2);
  int tid = threadIdx.x;

  // ---- group list ----
  int myng = 0, mylvl = 0, myG = 0;
  if (tid < NBLK) {
    int mv = mask[((long)h * NBLK + qi) * NBLK + tid];
    if (mv) {
      mylvl = (mv == 1) ? 0 : (mv == 2) ? 1 : (mv == 4) ? 2 : 3;
      myG = ((tid == NBLK - 1) ? VLAST : BLKSZ) >> mylvl;
      myng = (myG + 15) >> 4;
    }
    ngarr[tid] = myng;
  }
  __syncthreads();
  if (tid == 0) {
    int run = 0;
    for (int j = 0; j < NBLK; j++) { int t2 = ngarr[j]; ngarr[j] = run; run += t2; }
    int tot = run;
    while (tot & 3) glist[tot++] = 0;
    smeta = tot >> 2;
  }
  __syncthreads();
  if (tid < NBLK && myng) {
    int off = ngarr[tid];
    int src0, pooled;
    if (mylvl == 0) { src0 = h * LPAD + tid * BLKSZ; pooled = 0; }
    else {
      int loff = (mylvl == 1) ? 0 : (mylvl == 2) ? 64 : 96;
      src0 = (h * NBLK + tid) * 112 + loff; pooled = 1;
    }
    for (int g = 0; g < myng; g++) {
      int cnt = myG - 16 * g; if (cnt > 16) cnt = 16;
      glist[off + g] = (src0 + 16 * g) | (cnt << 24) | (mylvl << 29) | (pooled << 31);
    }
  }

  int lane = tid & 63, wid = tid >> 6;
  int lm = lane & 15, lg = lane >> 4;

  short8v Qf[2][2];
#pragma unroll
  for (int mt = 0; mt < 2; mt++)
#pragma unroll
    for (int ks = 0; ks < 2; ks++) {
      long row = (long)h * LPAD + qi * BLKSZ + wid * 32 + mt * 16 + lm;
      Qf[mt][ks] = *(const short8v*)(qrb + row * DD + ks * 32 + lg * 8);
    }

  f32x4 Oacc[4][2];
#pragma unroll
  for (int a = 0; a < 4; a++)
#pragma unroll
    for (int b = 0; b < 2; b++) { f32x4 z = {0.f, 0.f, 0.f, 0.f}; Oacc[a][b] = z; }
  float lrow0 = 0.f, lrow1 = 0.f;

  __syncthreads();
  int nchunks = smeta;

  int sr = tid & 63;
  int sd0 = (tid >> 6) * 16;

  short8v pkA, pkB, pvA, pvB;
  {
    unsigned e = (unsigned)glist[(sr >> 4)];
    long src = (long)((e & 0xFFFFFFu) + (sr & 15));
    const short* kb = (e >> 31) ? Kpb : krb;
    const short* vb = (e >> 31) ? Vpb : vrb;
    const short8v* kp = (const short8v*)(kb + src * DD + sd0);
    const short8v* vp = (const short8v*)(vb + src * DD + sd0);
    pkA = kp[0]; pkB = kp[1];
    pvA = vp[0]; pvB = vp[1];
  }

  for (int c = 0; c < nchunks; c++) {
    __syncthreads();
    {
      int sw = (sr & 7) << 3;
      *(short8v*)&Kt[sr * 64 + (sd0 ^ sw)] = pkA;
      *(short8v*)&Kt[sr * 64 + ((sd0 + 8) ^ sw)] = pkB;
#pragma unroll
      for (int i = 0; i < 8; i++) {
        Vt[(sd0 + i) * 68 + sr] = pvA[i];
        Vt[(sd0 + 8 + i) * 68 + sr] = pvB[i];
      }
    }
    __syncthreads();
    if (c + 1 < nchunks) {
      unsigned e = (unsigned)glist[4 * (c + 1) + (sr >> 4)];
      long src = (long)((e & 0xFFFFFFu) + (sr & 15));
      const short* kb = (e >> 31) ? Kpb : krb;
      const short* vb = (e >> 31) ? Vpb : vrb;
      const short8v* kp = (const short8v*)(kb + src * DD + sd0);
      const short8v* vp = (const short8v*)(vb + src * DD + sd0);
      pkA = kp[0]; pkB = kp[1];
      pvA = vp[0]; pvB = vp[1];
    }

    int cntv[4]; float biasv[4];
#pragma unroll
    for (int g = 0; g < 4; g++) {
      unsigned e = (unsigned)glist[4 * c + g];
      cntv[g] = (e >> 24) & 31;
      biasv[g] = (float)((e >> 29) & 3) * LN2F;
    }
    bool allfull = (cntv[0] == 16) & (cntv[1] == 16) & (cntv[2] == 16) & (cntv[3] == 16);

    short8v Kf[4][2];
#pragma unroll
    for (int nt = 0; nt < 4; nt++)
#pragma unroll
      for (int ks = 0; ks < 2; ks++)
        Kf[nt][ks] = *(short8v*)&Kt[(nt * 16 + lm) * 64 + ((ks * 32 + lg * 8) ^ ((lm & 7) << 3))];

    short8v Pf[2][2];
#pragma unroll
    for (int mt = 0; mt < 2; mt++) {
      f32x4 aq[4];
#pragma unroll
      for (int nt = 0; nt < 4; nt++) {
        f32x4 z = {0.f, 0.f, 0.f, 0.f};
        f32x4 a = __builtin_amdgcn_mfma_f32_16x16x32_bf16(Kf[nt][0], Qf[mt][0], z, 0, 0, 0);
        aq[nt] = __builtin_amdgcn_mfma_f32_16x16x32_bf16(Kf[nt][1], Qf[mt][1], a, 0, 0, 0);
      }
      float ps[16];
      if (allfull) {
#pragma unroll
        for (int nt = 0; nt < 4; nt++)
#pragma unroll
          for (int i = 0; i < 4; i++)
            ps[nt * 4 + i] = __expf(fmaf(aq[nt][i], SCALE, biasv[nt]));
      } else {
#pragma unroll
        for (int nt = 0; nt < 4; nt++)
#pragma unroll
          for (int i = 0; i < 4; i++) {
            int kvr = lg * 4 + i;
            ps[nt * 4 + i] = (kvr < cntv[nt]) ? __expf(fmaf(aq[nt][i], SCALE, biasv[nt])) : 0.f;
          }
      }
      float lsum = 0.f;
#pragma unroll
      for (int i = 0; i < 16; i++) lsum += ps[i];
      if (mt == 0) lrow0 += lsum; else lrow1 += lsum;
#pragma unroll
      for (int H = 0; H < 2; H++) {
        union { int i[4]; short8v v; } u;
        u.i[0] = cvtpk(ps[8 * H + 0], ps[8 * H + 1]);
        u.i[1] = cvtpk(ps[8 * H + 2], ps[8 * H + 3]);
        u.i[2] = cvtpk(ps[8 * H + 4], ps[8 * H + 5]);
        u.i[3] = cvtpk(ps[8 * H + 6], ps[8 * H + 7]);
        Pf[mt][H] = u.v;
      }
    }

#pragma unroll
    for (int mtp = 0; mtp < 4; mtp++) {
      int d68 = (mtp * 16 + lm) * 68;
#pragma unroll
      for (int H = 0; H < 2; H++) {
        short4 lo = *(short4*)&Vt[d68 + H * 32 + lg * 4];
        short4 hi = *(short4*)&Vt[d68 + H * 32 + 16 + lg * 4];
        short8v vf;
        vf[0] = lo.x; vf[1] = lo.y; vf[2] = lo.z; vf[3] = lo.w;
        vf[4] = hi.x; vf[5] = hi.y; vf[6] = hi.z; vf[7] = hi.w;
        Oacc[mtp][0] = __builtin_amdgcn_mfma_f32_16x16x32_bf16(vf, Pf[0][H], Oacc[mtp][0], 0, 0, 0);
        Oacc[mtp][1] = __builtin_amdgcn_mfma_f32_16x16x32_bf16(vf, Pf[1][H], Oacc[mtp][1], 0, 0, 0);
      }
    }
  }

  lrow0 += __shfl_xor(lrow0, 16); lrow0 += __shfl_xor(lrow0, 32);
  lrow1 += __shfl_xor(lrow1, 16); lrow1 += __shfl_xor(lrow1, 32);
  float inv0 = 1.0f / lrow0, inv1 = 1.0f / lrow1;
#pragma unroll
  for (int mt = 0; mt < 2; mt++) {
    int grow = qi * BLKSZ + wid * 32 + mt * 16 + lm;
    float inv = mt ? inv1 : inv0;
    float* orow = outr + ((long)h * LSEQ + grow) * DD;
#pragma unroll
    for (int mtp = 0; mtp < 4; mtp++) {
      f32x4 o = Oacc[mtp][mt];
      *(float4*)(orow + mtp * 16 + lg * 4) =
          make_float4(o[0] * inv, o[1] * inv, o[2] * inv, o[3] * inv);
    }
  }
}

// ---------------- MFMA sparse attention: HEAVY (full-attn) q-blocks ----------------
// 16 (h,qi) pairs x NSPLIT kv-slices; unnormalized partials.
__global__ __launch_bounds__(256, 1) void k_attn_heavy(
    const short* __restrict__ qrb, const short* __restrict__ krb,
    const short* __restrict__ vrb,
    float* __restrict__ part, float* __restrict__ plsum) {
  __shared__ __align__(16) short Kt[64 * 64];
  __shared__ __align__(16) short Vt[64 * 68];

  int bid = blockIdx.x;
  int split = bid & (NSPLIT - 1);
  int hq = bid / NSPLIT;           // 0..15
  int h = hq >> 1;
  int qi = NBLK - 2 + (hq & 1);
  int c0 = split * CHPER;
  int c1 = c0 + CHPER; if (c1 > HCHUNK) c1 = HCHUNK;
  int slot = hq * NSPLIT + split;
  int tid = threadIdx.x;

  int lane = tid & 63, wid = tid >> 6;
  int lm = lane & 15, lg = lane >> 4;

  short8v Qf[2][2];
#pragma unroll
  for (int mt = 0; mt < 2; mt++)
#pragma unroll
    for (int ks = 0; ks < 2; ks++) {
      long row = (long)h * LPAD + qi * BLKSZ + wid * 32 + mt * 16 + lm;
      Qf[mt][ks] = *(const short8v*)(qrb + row * DD + ks * 32 + lg * 8);
    }

  f32x4 Oacc[4][2];
#pragma unroll
  for (int a = 0; a < 4; a++)
#pragma unroll
    for (int b = 0; b < 2; b++) { f32x4 z = {0.f, 0.f, 0.f, 0.f}; Oacc[a][b] = z; }
  float lrow0 = 0.f, lrow1 = 0.f;

  int sr = tid & 63;
  int sd0 = (tid >> 6) * 16;

  short8v pkA, pkB, pvA, pvB;
  {
    long src = (long)h * LPAD + (long)c0 * 64 + sr;
    const short8v* kp = (const short8v*)(krb + src * DD + sd0);
    const short8v* vp = (const short8v*)(vrb + src * DD + sd0);
    pkA = kp[0]; pkB = kp[1];
    pvA = vp[0]; pvB = vp[1];
  }

  for (int c = c0; c < c1; c++) {
    __syncthreads();
    {
      int sw = (sr & 7) << 3;
      *(short8v*)&Kt[sr * 64 + (sd0 ^ sw)] = pkA;
      *(short8v*)&Kt[sr * 64 + ((sd0 + 8) ^ sw)] = pkB;
#pragma unroll
      for (int i = 0; i < 8; i++) {
        Vt[(sd0 + i) * 68 + sr] = pvA[i];
        Vt[(sd0 + 8 + i) * 68 + sr] = pvB[i];
      }
    }
    __syncthreads();
    if (c + 1 < c1) {
      long src = (long)h * LPAD + (long)(c + 1) * 64 + sr;
      const short8v* kp = (const short8v*)(krb + src * DD + sd0);
      const short8v* vp = (const short8v*)(vrb + src * DD + sd0);
      pkA = kp[0]; pkB = kp[1];
      pvA = vp[0]; pvB = vp[1];
    }

    bool allfull = (c != HCHUNK - 1);

    short8v Kf[4][2];
#pragma unroll
    for (int nt = 0; nt < 4; nt++)
#pragma unroll
      for (int ks = 0; ks < 2; ks++)
        Kf[nt][ks] = *(short8v*)&Kt[(nt * 16 + lm) * 64 + ((ks * 32 + lg * 8) ^ ((lm & 7) << 3))];

    short8v Pf[2][2];
#pragma unroll
    for (int mt = 0; mt < 2; mt++) {
      f32x4 aq[4];
#pragma unroll
      for (int nt = 0; nt < 4; nt++) {
        f32x4 z = {0.f, 0.f, 0.f, 0.f};
        f32x4 a = __builtin_amdgcn_mfma_f32_16x16x32_bf16(Kf[nt][0], Qf[mt][0], z, 0, 0, 0);
        aq[nt] = __builtin_amdgcn_mfma_f32_16x16x32_bf16(Kf[nt][1], Qf[mt][1], a, 0, 0, 0);
      }
      float ps[16];
      if (allfull) {
#pragma unroll
        for (int nt = 0; nt < 4; nt++)
#pragma unroll
          for (int i = 0; i < 4; i++)
            ps[nt * 4 + i] = __expf(aq[nt][i] * SCALE);
      } else {
#pragma unroll
        for (int nt = 0; nt < 4; nt++) {
          int cc = LSEQ - 16 * (4 * c + nt);
          int cnt = cc <= 0 ? 0 : (cc >= 16 ? 16 : cc);
#pragma unroll
          for (int i = 0; i < 4; i++) {
            int kvr = lg * 4 + i;
            ps[nt * 4 + i] = (kvr < cnt) ? __expf(aq[nt][i] * SCALE) : 0.f;
          }
        }
      }
      float lsum = 0.f;
#pragma unroll
      for (int i = 0; i < 16; i++) lsum += ps[i];
      if (mt == 0) lrow0 += lsum; else lrow1 += lsum;
#pragma unroll
      for (int H = 0; H < 2; H++) {
        union { int i[4]; short8v v; } u;
        u.i[0] = cvtpk(ps[8 * H + 0], ps[8 * H + 1]);
        u.i[1] = cvtpk(ps[8 * H + 2], ps[8 * H + 3]);
        u.i[2] = cvtpk(ps[8 * H + 4], ps[8 * H + 5]);
        u.i[3] = cvtpk(ps[8 * H + 6], ps[8 * H + 7]);
        Pf[mt][H] = u.v;
      }
    }

#pragma unroll
    for (int mtp = 0; mtp < 4; mtp++) {
      int d68 = (mtp * 16 + lm) * 68;
#pragma unroll
      for (int H = 0; H < 2; H++) {
        short4 lo = *(short4*)&Vt[d68 + H * 32 + lg * 4];
        short4 hi = *(short4*)&Vt[d68 + H * 32 + 16 + lg * 4];
        short8v vf;
        vf[0] = lo.x; vf[1] = lo.y; vf[2] = lo.z; vf[3] = lo.w;
        vf[4] = hi.x; vf[5] = hi.y; vf[6] = hi.z; vf[7] = hi.w;
        Oacc[mtp][0] = __builtin_amdgcn_mfma_f32_16x16x32_bf16(vf, Pf[0][H], Oacc[mtp][0], 0, 0, 0);
        Oacc[mtp][1] = __builtin_amdgcn_mfma_f32_16x16x32_bf16(vf, Pf[1][H], Oacc[mtp][1], 0, 0, 0);
      }
    }
  }

  lrow0 += __shfl_xor(lrow0, 16); lrow0 += __shfl_xor(lrow0, 32);
  lrow1 += __shfl_xor(lrow1, 16); lrow1 += __shfl_xor(lrow1, 32);
  if (lg == 0) {
    plsum[(long)slot * BLKSZ + wid * 32 + lm] = lrow0;
    plsum[(long)slot * BLKSZ + wid * 32 + 16 + lm] = lrow1;
  }
#pragma unroll
  for (int mt = 0; mt < 2; mt++) {
    int lrow = wid * 32 + mt * 16 + lm;
    float* orow = part + ((long)slot * BLKSZ + lrow) * DD;
#pragma unroll
    for (int mtp = 0; mtp < 4; mtp++) {
      f32x4 o = Oacc[mtp][mt];
      *(float4*)(orow + mtp * 16 + lg * 4) = make_float4(o[0], o[1], o[2], o[3]);
    }
  }
}

// combine heavy partials -> outr
__global__ __launch_bounds__(256) void k_combine(
    const float* __restrict__ part, const float* __restrict__ plsum,
    float* __restrict__ outr) {
  int hq = blockIdx.x;             // 0..15
  int h = hq >> 1;
  int qi = NBLK - 2 + (hq & 1);
  int t = threadIdx.x;
  int row = t >> 1;
  int dbase = (t & 1) * 32;
  float l = 0.f;
  for (int s = 0; s < NSPLIT; s++) l += plsum[(long)(hq * NSPLIT + s) * BLKSZ + row];
  int grow = qi * BLKSZ + row;
  if (grow >= LSEQ) return;
  float inv = 1.0f / l;
  float* orow = outr + ((long)h * LSEQ + grow) * DD;
  for (int d = dbase; d < dbase + 32; d += 4) {
    float4 acc = make_float4(0.f, 0.f, 0.f, 0.f);
    for (int s = 0; s < NSPLIT; s++) {
      float4 p4 = *(const float4*)&part[((long)(hq * NSPLIT + s) * BLKSZ + row) * DD + d];
      acc.x += p4.x; acc.y += p4.y; acc.z += p4.z; acc.w += p4.w;
    }
    *(float4*)(orow + d) = make_float4(acc.x * inv, acc.y * inv, acc.z * inv, acc.w * inv);
  }
}

// final gather
__global__ __launch_bounds__(256) void k_out(
    const float* __restrict__ outr, const int* __restrict__ outg,
    float* __restrict__ out) {
  long rid = (long)blockIdx.x * 4 + (threadIdx.x >> 6);
  int d = threadIdx.x & 63;
  const long total = (long)NH * LSEQ;
  if (rid >= total) return;
  int h = (int)(rid / LSEQ);
  int r = (int)(rid % LSEQ);
  int src = outg[r];
  out[((long)h * LSEQ + r) * DD + d] = outr[((long)h * LSEQ + src) * DD + d];
}

// ============================ launch ============================

extern "C" void kernel_launch(void* const* d_in, const int* in_sizes, int n_in,
                              void* d_out, int out_size, void* d_ws, size_t ws_size,
                              hipStream_t stream) {
  (void)in_sizes; (void)n_in; (void)out_size; (void)ws_size;
  const float* q = (const float*)d_in[0];
  const float* k = (const float*)d_in[1];
  const float* v = (const float*)d_in[2];
  float* ws = (float*)d_ws;
  float* out = (float*)d_out;

  static int* htab = nullptr;
  if (!htab) { (void)hipHostMalloc((void**)&htab, TAB_INTS * sizeof(int)); }
  build_tables(htab);

  int* dtab = (int*)(ws + F_TB);
  int* inmap = dtab;
  int* outg = dtab + LSEQ;
  int* qidx = dtab + 2 * LSEQ;
  int* kidx = qidx + NH * NKEEP;
  int* dmask = (int*)(ws + F_MK);
  float* qr = ws + F_QR; float* kr = ws + F_KR;
  short* qrb = (short*)(ws + F_QB);
  short* krb = (short*)(ws + F_KB);
  short* vrb = (short*)(ws + F_VB);
  float* sq = ws + F_SQ; float* sk = ws + F_SK; float* pool = ws + F_PL;
  short* Kpb = (short*)(ws + F_KPB);
  short* Vpb = (short*)(ws + F_VPB);
  float* outr = ws + F_OR;
  float* part = ws + F_PT;
  float* plsum = ws + F_PS;

  hipMemcpyAsync(dtab, htab, TAB_INTS * sizeof(int), hipMemcpyHostToDevice, stream);

  {
    long rows = 3L * NH * LPAD;
    k_rearr<<<dim3((unsigned)((rows + 3) / 4)), 256, 0, stream>>>(
        q, k, v, qr, kr, qrb, krb, vrb, inmap);
  }
  {
    long rows = 2L * NH * NS;
    k_sample<<<dim3((unsigned)((rows + 3) / 4)), 256, 0, stream>>>(qr, kr, sq, sk, qidx, kidx);
  }
  k_scores_pool<<<dim3(NH * NBLK), 256, 0, stream>>>(sq, sk, pool);
  k_mask<<<dim3(NH * NBLK), 192, 0, stream>>>(pool, dmask);
  {
    long rows = 2L * NH * NBLK * 112;
    k_poolkv<<<dim3((unsigned)((rows + 3) / 4)), 256, 0, stream>>>(krb, vrb, Kpb, Vpb);
  }
  k_attn_heavy<<<dim3(NHEAVYB), 256, 0, stream>>>(qrb, krb, vrb, part, plsum);
  k_attn_light<<<dim3(NLIGHT), 256, 0, stream>>>(qrb, krb, vrb, Kpb, Vpb, dmask, outr);
  k_combine<<<dim3(NH * 2), 256, 0, stream>>>(part, plsum, outr);
  {
    long rows = (long)NH * LSEQ;
    k_out<<<dim3((unsigned)((rows + 3) / 4)), 256, 0, stream>>>(outr, outg, out);
  }
}